// Round 2
// baseline (2418.277 us; speedup 1.0000x reference)
//
#include <hip/hip_runtime.h>

#define A_TOTAL  200000
#define BSEG     100
#define FR_      256
#define DIN_     512
#define H_       256
#define P_       6
#define TA       96
#define NTHREADS 512

typedef float f32x4  __attribute__((ext_vector_type(4)));
typedef short bf16x8 __attribute__((ext_vector_type(8)));

__device__ __forceinline__ unsigned short f2bf(float x) {
    union { float f; unsigned int u; } c; c.f = x;
    unsigned int u = c.u;
    return (unsigned short)((u + 0x7fffu + ((u >> 16) & 1u)) >> 16);
}
__device__ __forceinline__ float bf2f(unsigned short b) {
    union { unsigned int u; float f; } c; c.u = ((unsigned int)b) << 16;
    return c.f;
}
__device__ __forceinline__ float fast_tanh(float x) {
    float e = __expf(2.f * x);
    return 1.f - 2.f / (e + 1.f);
}
// XOR swizzle: spreads rows (stride 1024B / 512B, all bank-aligned) across 8
// distinct 16B slots so frag ds_read_b128 (lanes 0-15 = 16 rows) is 2-way max.
__device__ __forceinline__ int swzNI(int row, int kb) { return row * 1024 + (kb ^ ((row & 7) << 4)); }
__device__ __forceinline__ int swzH (int row, int kb) { return row * 512  + (kb ^ ((row & 7) << 4)); }

__device__ __forceinline__ f32x4 mfma16(bf16x8 a, bf16x8 b, f32x4 c) {
    return __builtin_amdgcn_mfma_f32_16x16x32_bf16(a, b, c, 0, 0, 0);
}

// ---------------------------------------------------------------------------
// Prep: W1/W2 -> bf16 fragment-linear layout; prefix-sum num_angles; zero out.
// B-frag for 16x16x32: lane l holds B[k = s*32 + 8*(l>>4) + j][n = nt*16 + (l&15)]
// stored as wt[p][s][nt][l][j] (16B per lane -> coalesced 1KB wave loads).
// ---------------------------------------------------------------------------
__global__ void prep_kernel(const float* __restrict__ W1, const float* __restrict__ W2,
                            const int* __restrict__ num_angles, float* __restrict__ out,
                            int* __restrict__ prefix,
                            unsigned short* __restrict__ wt1, unsigned short* __restrict__ wt2) {
    int tt = blockIdx.x * blockDim.x + threadIdx.x;
    if (blockIdx.x == 0) {
        if (threadIdx.x < BSEG) out[threadIdx.x] = 0.f;
        if (threadIdx.x == 0) {
            int acc = 0; prefix[0] = 0;
            for (int i = 0; i < BSEG; ++i) { acc += num_angles[i]; prefix[i + 1] = acc; }
        }
    }
    if (tt < 98304) {                       // W1: 6 p * 16 s * 16 nt * 64 lanes
        int l  = tt & 63;
        int nt = (tt >> 6) & 15;
        int s  = (tt >> 10) & 15;
        int p  = tt >> 14;
        int k  = s * 32 + 8 * (l >> 4);
        int n  = nt * 16 + (l & 15);
        const float* src = W1 + ((size_t)p * DIN_ + k) * H_ + n;
        unsigned short tmp[8];
#pragma unroll
        for (int j = 0; j < 8; ++j) tmp[j] = f2bf(src[(size_t)j * H_]);
        *reinterpret_cast<uint4*>(wt1 + (size_t)tt * 8) = *reinterpret_cast<uint4*>(tmp);
    } else if (tt < 98304 + 49152) {        // W2: 6 p * 8 s * 16 nt * 64 lanes
        int t2 = tt - 98304;
        int l  = t2 & 63;
        int nt = (t2 >> 6) & 15;
        int s  = (t2 >> 10) & 7;
        int p  = t2 >> 13;
        int k  = s * 32 + 8 * (l >> 4);
        int n  = nt * 16 + (l & 15);
        const float* src = W2 + ((size_t)p * H_ + k) * H_ + n;
        unsigned short tmp[8];
#pragma unroll
        for (int j = 0; j < 8; ++j) tmp[j] = f2bf(src[(size_t)j * H_]);
        *reinterpret_cast<uint4*>(wt2 + (size_t)t2 * 8) = *reinterpret_cast<uint4*>(tmp);
    }
}

// ---------------------------------------------------------------------------
// Main fused kernel: TA=96 angles per block, 8 waves.
// ---------------------------------------------------------------------------
__global__ __launch_bounds__(NTHREADS, 1)
void angle_main(const float* __restrict__ r, const float* __restrict__ xyz,
                const int* __restrict__ ang,
                const float* __restrict__ b1, const float* __restrict__ b2,
                const float* __restrict__ W3, const float* __restrict__ b3,
                float* __restrict__ out, const int* __restrict__ prefix,
                const unsigned short* __restrict__ wt1, const unsigned short* __restrict__ wt2) {
    __shared__ unsigned short sNI[TA * DIN_];   // 96 KB, swizzled bf16 node_input
    __shared__ unsigned short sH[TA * H_];      // 48 KB, swizzled bf16 H1 then H2
    __shared__ float sPart[4 * TA];             // layer-3 partial dots
    __shared__ float sOut[P_ * TA];             // per-p MLP scalar outputs
    __shared__ float sSeg[BSEG];                // per-block segment bins

    const int tid  = threadIdx.x;
    const int lane = tid & 63;
    const int w    = tid >> 6;
    const int Mg   = w & 1;        // 2 M-groups * 48 rows
    const int Ng   = w >> 1;       // 4 N-groups * 64 cols
    const int aB   = blockIdx.x * TA;
    char* cNI = (char*)sNI;
    char* cH  = (char*)sH;

    // ---- gather node_input = [r[a0]+r[a2], r[a1]] -> LDS bf16 (swizzled) ----
#pragma unroll
    for (int it = 0; it < 12; ++it) {
        int c   = it * NTHREADS + tid;       // 6144 chunks of 8 elems
        int row = c >> 6;
        int k0  = (c & 63) * 8;
        int a   = aB + row;
        float v[8];
        if (a < A_TOTAL) {
            int i0 = ang[3 * a], i1 = ang[3 * a + 1], i2 = ang[3 * a + 2];
            if (k0 < FR_) {
                const float4* p0 = (const float4*)(r + (size_t)i0 * FR_ + k0);
                const float4* p2 = (const float4*)(r + (size_t)i2 * FR_ + k0);
                float4 x0 = p0[0], x1 = p0[1], y0 = p2[0], y1 = p2[1];
                v[0] = x0.x + y0.x; v[1] = x0.y + y0.y; v[2] = x0.z + y0.z; v[3] = x0.w + y0.w;
                v[4] = x1.x + y1.x; v[5] = x1.y + y1.y; v[6] = x1.z + y1.z; v[7] = x1.w + y1.w;
            } else {
                const float4* p1 = (const float4*)(r + (size_t)i1 * FR_ + (k0 - FR_));
                float4 x0 = p1[0], x1 = p1[1];
                v[0] = x0.x; v[1] = x0.y; v[2] = x0.z; v[3] = x0.w;
                v[4] = x1.x; v[5] = x1.y; v[6] = x1.z; v[7] = x1.w;
            }
        } else {
#pragma unroll
            for (int j = 0; j < 8; ++j) v[j] = 0.f;
        }
        unsigned short u[8];
#pragma unroll
        for (int j = 0; j < 8; ++j) u[j] = f2bf(v[j]);
        *reinterpret_cast<uint4*>(cNI + swzNI(row, k0 * 2)) = *reinterpret_cast<uint4*>(u);
    }
    __syncthreads();

    for (int p = 0; p < P_; ++p) {
        // ---------------- layer 1: [96x512] @ [512x256] ----------------
        f32x4 acc[3][4];
#pragma unroll
        for (int mt = 0; mt < 3; ++mt)
#pragma unroll
            for (int nt = 0; nt < 4; ++nt) acc[mt][nt] = (f32x4){0.f, 0.f, 0.f, 0.f};
        const unsigned short* B1 = wt1 + (size_t)p * 131072;   // 16*16*64*8
#pragma unroll
        for (int s = 0; s < 16; ++s) {
            int kb = (s * 32 + 8 * (lane >> 4)) * 2;
            bf16x8 af[3];
#pragma unroll
            for (int mt = 0; mt < 3; ++mt)
                af[mt] = *(const bf16x8*)(cNI + swzNI(Mg * 48 + mt * 16 + (lane & 15), kb));
#pragma unroll
            for (int nt = 0; nt < 4; ++nt) {
                bf16x8 bfr = *(const bf16x8*)(B1 + (size_t)((s * 16 + Ng * 4 + nt) * 64 + lane) * 8);
#pragma unroll
                for (int mt = 0; mt < 3; ++mt) acc[mt][nt] = mfma16(af[mt], bfr, acc[mt][nt]);
            }
        }
        {   // bias + tanh + write H1 (D layout: row = 4*(l>>4)+i, col = l&15)
            const float* bp = b1 + p * H_;
#pragma unroll
            for (int nt = 0; nt < 4; ++nt) {
                int col = Ng * 64 + nt * 16 + (lane & 15);
                float bias = bp[col];
#pragma unroll
                for (int mt = 0; mt < 3; ++mt) {
                    int rb = Mg * 48 + mt * 16 + 4 * (lane >> 4);
#pragma unroll
                    for (int i = 0; i < 4; ++i) {
                        float hx = fast_tanh(acc[mt][nt][i] + bias);
                        *(unsigned short*)(cH + swzH(rb + i, col * 2)) = f2bf(hx);
                    }
                }
            }
        }
        __syncthreads();

        // ---------------- layer 2: [96x256] @ [256x256] ----------------
        f32x4 acc2[3][4];
#pragma unroll
        for (int mt = 0; mt < 3; ++mt)
#pragma unroll
            for (int nt = 0; nt < 4; ++nt) acc2[mt][nt] = (f32x4){0.f, 0.f, 0.f, 0.f};
        const unsigned short* B2 = wt2 + (size_t)p * 65536;    // 8*16*64*8
#pragma unroll
        for (int s = 0; s < 8; ++s) {
            int kb = (s * 32 + 8 * (lane >> 4)) * 2;
            bf16x8 af[3];
#pragma unroll
            for (int mt = 0; mt < 3; ++mt)
                af[mt] = *(const bf16x8*)(cH + swzH(Mg * 48 + mt * 16 + (lane & 15), kb));
#pragma unroll
            for (int nt = 0; nt < 4; ++nt) {
                bf16x8 bfr = *(const bf16x8*)(B2 + (size_t)((s * 16 + Ng * 4 + nt) * 64 + lane) * 8);
#pragma unroll
                for (int mt = 0; mt < 3; ++mt) acc2[mt][nt] = mfma16(af[mt], bfr, acc2[mt][nt]);
            }
        }
        __syncthreads();   // all H1 reads done before overwriting with H2
        {
            const float* bp = b2 + p * H_;
#pragma unroll
            for (int nt = 0; nt < 4; ++nt) {
                int col = Ng * 64 + nt * 16 + (lane & 15);
                float bias = bp[col];
#pragma unroll
                for (int mt = 0; mt < 3; ++mt) {
                    int rb = Mg * 48 + mt * 16 + 4 * (lane >> 4);
#pragma unroll
                    for (int i = 0; i < 4; ++i) {
                        float hx = fast_tanh(acc2[mt][nt][i] + bias);
                        *(unsigned short*)(cH + swzH(rb + i, col * 2)) = f2bf(hx);
                    }
                }
            }
        }
        __syncthreads();

        // ---------------- layer 3: out[p][a] = H2[a,:] . W3[p] + b3[p] ----
        if (tid < 4 * TA) {
            int al = tid >> 2, q = tid & 3;
            const float* w3p = W3 + p * H_;
            float sum = 0.f;
#pragma unroll
            for (int j = 0; j < 8; ++j) {
                int k = q * 64 + j * 8;
                bf16x8 hv = *(const bf16x8*)(cH + swzH(al, k * 2));
#pragma unroll
                for (int e = 0; e < 8; ++e)
                    sum += bf2f((unsigned short)hv[e]) * w3p[k + e];
            }
            sPart[q * TA + al] = sum;
        }
        __syncthreads();
        if (tid < TA)
            sOut[p * TA + tid] = sPart[tid] + sPart[TA + tid] + sPart[2 * TA + tid] + sPart[3 * TA + tid] + b3[p];
        __syncthreads();
    }

    // ---------------- geometry + energy + segment sum ----------------
    if (tid < BSEG) sSeg[tid] = 0.f;
    __syncthreads();
    if (tid < TA && (aB + tid) < A_TOTAL) {
        int a = aB + tid;
        int i0 = ang[3 * a], i1 = ang[3 * a + 1], i2 = ang[3 * a + 2];
        float ax = xyz[3 * i0], ay = xyz[3 * i0 + 1], az = xyz[3 * i0 + 2];
        float bx = xyz[3 * i1], by = xyz[3 * i1 + 1], bz = xyz[3 * i1 + 2];
        float cx = xyz[3 * i2], cy = xyz[3 * i2 + 1], cz = xyz[3 * i2 + 2];
        float v1x = bx - ax, v1y = by - ay, v1z = bz - az;
        float v2x = cx - bx, v2y = cy - by, v2z = cz - bz;
        float dot = -(v1x * v2x + v1y * v2y + v1z * v2z);
        float n1  = v1x * v1x + v1y * v1y + v1z * v1z;
        float n2  = v2x * v2x + v2y * v2y + v2z * v2z;
        float ct  = dot / sqrtf(n1 * n2);
        float th  = acosf(ct / 1.000001f);

        float o0 = sOut[0 * TA + tid], o1 = sOut[1 * TA + tid], o2 = sOut[2 * TA + tid];
        float o3 = sOut[3 * TA + tid], o4 = sOut[4 * TA + tid], o5 = sOut[5 * TA + tid];
        float t0h = (1.38243827f + o0); t0h *= t0h;       // (sqrt(109.5*pi/180)+o0)^2
        float kh  = (3.16227766f + o1); kh  *= kh;        // (sqrt(10)+o1)^2
        float d   = th - t0h;
        float E   = 0.5f * kh * d * d;
        float t0c = o2 * o2, kc = o3 * o3;
        float dc  = th - t0c;
        E += 0.5f * kc * dc * dc * dc;
        float t0q = o4 * o4, kq = o5 * o5;
        float dq  = th - t0q;
        E += 0.5f * kq * dq * dq * dq * dq;

        int lo = 0, hi = BSEG - 1;                        // last s with prefix[s] <= a
        while (lo < hi) { int mid = (lo + hi + 1) >> 1; if (prefix[mid] <= a) lo = mid; else hi = mid - 1; }
        atomicAdd(&sSeg[lo], E);
    }
    __syncthreads();
    if (tid < BSEG) {
        float v = sSeg[tid];
        if (v != 0.f) atomicAdd(out + tid, v);
    }
}

extern "C" void kernel_launch(void* const* d_in, const int* in_sizes, int n_in,
                              void* d_out, int out_size, void* d_ws, size_t ws_size,
                              hipStream_t stream) {
    const float* r   = (const float*)d_in[0];
    const float* xyz = (const float*)d_in[1];
    const int*   ang = (const int*)d_in[2];
    const int*   na  = (const int*)d_in[3];
    const float* W1  = (const float*)d_in[4];
    const float* b1  = (const float*)d_in[5];
    const float* W2  = (const float*)d_in[6];
    const float* b2  = (const float*)d_in[7];
    const float* W3  = (const float*)d_in[8];
    const float* b3  = (const float*)d_in[9];
    float* out = (float*)d_out;

    char* ws = (char*)d_ws;
    int* prefix          = (int*)ws;                              // 101 ints (512B reserved)
    unsigned short* wt1  = (unsigned short*)(ws + 512);           // 1.5 MB bf16 frag-linear
    unsigned short* wt2  = (unsigned short*)(ws + 512 + 1572864); // 0.75 MB

    prep_kernel<<<576, 256, 0, stream>>>(W1, W2, na, out, prefix, wt1, wt2);
    int nblk = (A_TOTAL + TA - 1) / TA;   // 2084
    angle_main<<<nblk, NTHREADS, 0, stream>>>(r, xyz, ang, b1, b2, W3, b3, out, prefix, wt1, wt2);
}

// Round 4
// 1132.875 us; speedup vs baseline: 2.1346x; 2.1346x over previous
//
#include <hip/hip_runtime.h>

#define A_TOTAL  200000
#define BSEG     100
#define FR_      256
#define DIN_     512
#define H_       256
#define P_       6
#define TA       48
#define NTHREADS 512

typedef float f32x4  __attribute__((ext_vector_type(4)));
typedef short bf16x8 __attribute__((ext_vector_type(8)));

__device__ __forceinline__ unsigned short f2bf(float x) {
    union { float f; unsigned int u; } c; c.f = x;
    unsigned int u = c.u;
    return (unsigned short)((u + 0x7fffu + ((u >> 16) & 1u)) >> 16);
}
__device__ __forceinline__ float fast_tanh(float x) {
    float e = __expf(2.f * x);
    return 1.f - 2.f / (e + 1.f);
}
// XOR swizzle: rows are bank-aligned (1024B/512B stride); XOR row into the
// 16B-slot bits so a 16-row ds_read_b128 column-slice is <=2-way.
__device__ __forceinline__ int swzNI(int row, int kb) { return row * 1024 + (kb ^ ((row & 7) << 4)); }
__device__ __forceinline__ int swzH (int row, int kb) { return row * 512  + (kb ^ ((row & 7) << 4)); }

__device__ __forceinline__ f32x4 mfma16(bf16x8 a, bf16x8 b, f32x4 c) {
    return __builtin_amdgcn_mfma_f32_16x16x32_bf16(a, b, c, 0, 0, 0);
}

// ---------------------------------------------------------------------------
// Prep: W1/W2 -> bf16 fragment-linear layout; prefix-sum num_angles; zero out.
// B-frag for 16x16x32: lane l holds B[k = s*32 + 8*(l>>4) + j][n = nt*16 + (l&15)]
// stored as wt[p][s][nt][l][j] (16B per lane -> coalesced 1KB wave loads).
// ---------------------------------------------------------------------------
__global__ void prep_kernel(const float* __restrict__ W1, const float* __restrict__ W2,
                            const int* __restrict__ num_angles, float* __restrict__ out,
                            int* __restrict__ prefix,
                            unsigned short* __restrict__ wt1, unsigned short* __restrict__ wt2) {
    int tt = blockIdx.x * blockDim.x + threadIdx.x;
    if (blockIdx.x == 0) {
        if (threadIdx.x < BSEG) out[threadIdx.x] = 0.f;
        if (threadIdx.x == 0) {
            int acc = 0; prefix[0] = 0;
            for (int i = 0; i < BSEG; ++i) { acc += num_angles[i]; prefix[i + 1] = acc; }
        }
    }
    if (tt < 98304) {                       // W1: 6 p * 16 s * 16 nt * 64 lanes
        int l  = tt & 63;
        int nt = (tt >> 6) & 15;
        int s  = (tt >> 10) & 15;
        int p  = tt >> 14;
        int k  = s * 32 + 8 * (l >> 4);
        int n  = nt * 16 + (l & 15);
        const float* src = W1 + ((size_t)p * DIN_ + k) * H_ + n;
        unsigned short tmp[8];
#pragma unroll
        for (int j = 0; j < 8; ++j) tmp[j] = f2bf(src[(size_t)j * H_]);
        *reinterpret_cast<uint4*>(wt1 + (size_t)tt * 8) = *reinterpret_cast<uint4*>(tmp);
    } else if (tt < 98304 + 49152) {        // W2: 6 p * 8 s * 16 nt * 64 lanes
        int t2 = tt - 98304;
        int l  = t2 & 63;
        int nt = (t2 >> 6) & 15;
        int s  = (t2 >> 10) & 7;
        int p  = t2 >> 13;
        int k  = s * 32 + 8 * (l >> 4);
        int n  = nt * 16 + (l & 15);
        const float* src = W2 + ((size_t)p * H_ + k) * H_ + n;
        unsigned short tmp[8];
#pragma unroll
        for (int j = 0; j < 8; ++j) tmp[j] = f2bf(src[(size_t)j * H_]);
        *reinterpret_cast<uint4*>(wt2 + (size_t)t2 * 8) = *reinterpret_cast<uint4*>(tmp);
    }
}

// ---------------------------------------------------------------------------
// Main fused kernel: TA=48 angles/block, 8 waves, each wave = 48 rows x 32 cols.
// LDS ~75 KB -> 2 blocks/CU. 2 barriers per p.
// ---------------------------------------------------------------------------
__global__ __launch_bounds__(NTHREADS, 4)
void angle_main(const float* __restrict__ r, const float* __restrict__ xyz,
                const int* __restrict__ ang,
                const float* __restrict__ b1, const float* __restrict__ b2,
                const float* __restrict__ W3, const float* __restrict__ b3,
                float* __restrict__ out, const int* __restrict__ prefix,
                const unsigned short* __restrict__ wt1, const unsigned short* __restrict__ wt2) {
    __shared__ unsigned short sNI[TA * DIN_];   // 48 KB, swizzled bf16 node_input
    __shared__ unsigned short sH[TA * H_];      // 24 KB, swizzled bf16 H1
    __shared__ float sOut[P_ * TA];             // per-p MLP scalar outputs (atomic acc)
    __shared__ float sSeg[BSEG];                // per-block segment bins

    const int tid  = threadIdx.x;
    const int lane = tid & 63;
    const int w    = tid >> 6;     // wave id: owns cols [w*32, w*32+32)
    const int aB   = blockIdx.x * TA;
    char* cNI = (char*)sNI;
    char* cH  = (char*)sH;

    if (tid < P_ * TA) sOut[tid] = 0.f;
    if (tid < BSEG)    sSeg[tid] = 0.f;

    // ---- gather node_input = [r[a0]+r[a2], r[a1]] -> LDS bf16 (swizzled) ----
#pragma unroll
    for (int it = 0; it < 6; ++it) {
        int c   = it * NTHREADS + tid;       // 3072 chunks of 8 elems
        int row = c >> 6;
        int k0  = (c & 63) * 8;
        int a   = aB + row;
        float v[8];
        if (a < A_TOTAL) {
            int i0 = ang[3 * a], i1 = ang[3 * a + 1], i2 = ang[3 * a + 2];
            if (k0 < FR_) {
                const float4* p0 = (const float4*)(r + (size_t)i0 * FR_ + k0);
                const float4* p2 = (const float4*)(r + (size_t)i2 * FR_ + k0);
                float4 x0 = p0[0], x1 = p0[1], y0 = p2[0], y1 = p2[1];
                v[0] = x0.x + y0.x; v[1] = x0.y + y0.y; v[2] = x0.z + y0.z; v[3] = x0.w + y0.w;
                v[4] = x1.x + y1.x; v[5] = x1.y + y1.y; v[6] = x1.z + y1.z; v[7] = x1.w + y1.w;
            } else {
                const float4* p1 = (const float4*)(r + (size_t)i1 * FR_ + (k0 - FR_));
                float4 x0 = p1[0], x1 = p1[1];
                v[0] = x0.x; v[1] = x0.y; v[2] = x0.z; v[3] = x0.w;
                v[4] = x1.x; v[5] = x1.y; v[6] = x1.z; v[7] = x1.w;
            }
        } else {
#pragma unroll
            for (int j = 0; j < 8; ++j) v[j] = 0.f;
        }
        unsigned short u[8];
#pragma unroll
        for (int j = 0; j < 8; ++j) u[j] = f2bf(v[j]);
        *reinterpret_cast<uint4*>(cNI + swzNI(row, k0 * 2)) = *reinterpret_cast<uint4*>(u);
    }
    __syncthreads();

    for (int p = 0; p < P_; ++p) {
        // ---------------- layer 1: [48x512] @ [512x256], wave cols w*32.. ----
        f32x4 acc[3][2];
#pragma unroll
        for (int mt = 0; mt < 3; ++mt)
#pragma unroll
            for (int nt = 0; nt < 2; ++nt) acc[mt][nt] = (f32x4){0.f, 0.f, 0.f, 0.f};
        const unsigned short* B1 = wt1 + (size_t)p * 131072;
#pragma unroll
        for (int s = 0; s < 16; ++s) {
            int kb = (s * 32 + 8 * (lane >> 4)) * 2;
            bf16x8 af[3];
#pragma unroll
            for (int mt = 0; mt < 3; ++mt)
                af[mt] = *(const bf16x8*)(cNI + swzNI(mt * 16 + (lane & 15), kb));
#pragma unroll
            for (int nt = 0; nt < 2; ++nt) {
                int ntile = w * 2 + nt;
                bf16x8 bfr = *(const bf16x8*)(B1 + (size_t)((s * 16 + ntile) * 64 + lane) * 8);
#pragma unroll
                for (int mt = 0; mt < 3; ++mt) acc[mt][nt] = mfma16(af[mt], bfr, acc[mt][nt]);
            }
        }
        {   // bias + tanh + write H1 (D layout: row = 4*(l>>4)+i, col = l&15)
            const float* bp = b1 + p * H_;
#pragma unroll
            for (int nt = 0; nt < 2; ++nt) {
                int col = w * 32 + nt * 16 + (lane & 15);
                float bias = bp[col];
#pragma unroll
                for (int mt = 0; mt < 3; ++mt) {
                    int rb = mt * 16 + 4 * (lane >> 4);
#pragma unroll
                    for (int i = 0; i < 4; ++i) {
                        float hx = fast_tanh(acc[mt][nt][i] + bias);
                        *(unsigned short*)(cH + swzH(rb + i, col * 2)) = f2bf(hx);
                    }
                }
            }
        }
        __syncthreads();

        // ---------------- layer 2: [48x256] @ [256x256] ----------------
        f32x4 acc2[3][2];
#pragma unroll
        for (int mt = 0; mt < 3; ++mt)
#pragma unroll
            for (int nt = 0; nt < 2; ++nt) acc2[mt][nt] = (f32x4){0.f, 0.f, 0.f, 0.f};
        const unsigned short* B2 = wt2 + (size_t)p * 65536;
#pragma unroll
        for (int s = 0; s < 8; ++s) {
            int kb = (s * 32 + 8 * (lane >> 4)) * 2;
            bf16x8 af[3];
#pragma unroll
            for (int mt = 0; mt < 3; ++mt)
                af[mt] = *(const bf16x8*)(cH + swzH(mt * 16 + (lane & 15), kb));
#pragma unroll
            for (int nt = 0; nt < 2; ++nt) {
                int ntile = w * 2 + nt;
                bf16x8 bfr = *(const bf16x8*)(B2 + (size_t)((s * 16 + ntile) * 64 + lane) * 8);
#pragma unroll
                for (int mt = 0; mt < 3; ++mt) acc2[mt][nt] = mfma16(af[mt], bfr, acc2[mt][nt]);
            }
        }

        // ---- layer 3 from registers: out[p][a] = sum_n tanh(acc2+b2)[a][n]*w3[n] ----
        {
            const float* bp2 = b2 + p * H_;
            const float* w3p = W3 + p * H_;
            float prt[12];
#pragma unroll
            for (int k = 0; k < 12; ++k) prt[k] = 0.f;
#pragma unroll
            for (int nt = 0; nt < 2; ++nt) {
                int col = w * 32 + nt * 16 + (lane & 15);
                float bias = bp2[col];
                float wv   = w3p[col];
#pragma unroll
                for (int mt = 0; mt < 3; ++mt)
#pragma unroll
                    for (int i = 0; i < 4; ++i)
                        prt[mt * 4 + i] += fast_tanh(acc2[mt][nt][i] + bias) * wv;
            }
#pragma unroll
            for (int st = 1; st < 16; st <<= 1)
#pragma unroll
                for (int k = 0; k < 12; ++k) prt[k] += __shfl_xor(prt[k], st);
            if ((lane & 15) == 0) {
                int rg = 4 * (lane >> 4);
#pragma unroll
                for (int mt = 0; mt < 3; ++mt)
#pragma unroll
                    for (int i = 0; i < 4; ++i)
                        atomicAdd(&sOut[p * TA + mt * 16 + rg + i], prt[mt * 4 + i]);
            }
        }
        __syncthreads();   // sH reads done (next p overwrites) + sOut[p] visible
    }

    // ---------------- geometry + energy + segment sum ----------------
    if (tid < TA && (aB + tid) < A_TOTAL) {
        int a = aB + tid;
        int i0 = ang[3 * a], i1 = ang[3 * a + 1], i2 = ang[3 * a + 2];
        float ax = xyz[3 * i0], ay = xyz[3 * i0 + 1], az = xyz[3 * i0 + 2];
        float bx = xyz[3 * i1], by = xyz[3 * i1 + 1], bz = xyz[3 * i1 + 2];
        float cx = xyz[3 * i2], cy = xyz[3 * i2 + 1], cz = xyz[3 * i2 + 2];
        float v1x = bx - ax, v1y = by - ay, v1z = bz - az;
        float v2x = cx - bx, v2y = cy - by, v2z = cz - bz;
        float dot = -(v1x * v2x + v1y * v2y + v1z * v2z);
        float n1  = v1x * v1x + v1y * v1y + v1z * v1z;
        float n2  = v2x * v2x + v2y * v2y + v2z * v2z;
        float ct  = dot / sqrtf(n1 * n2);
        float th  = acosf(ct / 1.000001f);

        float o0 = sOut[0 * TA + tid] + b3[0], o1 = sOut[1 * TA + tid] + b3[1];
        float o2 = sOut[2 * TA + tid] + b3[2], o3 = sOut[3 * TA + tid] + b3[3];
        float o4 = sOut[4 * TA + tid] + b3[4], o5 = sOut[5 * TA + tid] + b3[5];
        float t0h = (1.38243827f + o0); t0h *= t0h;       // (sqrt(109.5*pi/180)+o0)^2
        float kh  = (3.16227766f + o1); kh  *= kh;        // (sqrt(10)+o1)^2
        float d   = th - t0h;
        float E   = 0.5f * kh * d * d;
        float t0c = o2 * o2, kc = o3 * o3;
        float dc  = th - t0c;
        E += 0.5f * kc * dc * dc * dc;
        float t0q = o4 * o4, kq = o5 * o5;
        float dq  = th - t0q;
        E += 0.5f * kq * dq * dq * dq * dq;

        int lo = 0, hi = BSEG - 1;                        // last s with prefix[s] <= a
        while (lo < hi) { int mid = (lo + hi + 1) >> 1; if (prefix[mid] <= a) lo = mid; else hi = mid - 1; }
        atomicAdd(&sSeg[lo], E);
    }
    __syncthreads();
    if (tid < BSEG) {
        float v = sSeg[tid];
        if (v != 0.f) atomicAdd(out + tid, v);
    }
}

extern "C" void kernel_launch(void* const* d_in, const int* in_sizes, int n_in,
                              void* d_out, int out_size, void* d_ws, size_t ws_size,
                              hipStream_t stream) {
    const float* r   = (const float*)d_in[0];
    const float* xyz = (const float*)d_in[1];
    const int*   ang = (const int*)d_in[2];
    const int*   na  = (const int*)d_in[3];
    const float* W1  = (const float*)d_in[4];
    const float* b1  = (const float*)d_in[5];
    const float* W2  = (const float*)d_in[6];
    const float* b2  = (const float*)d_in[7];
    const float* W3  = (const float*)d_in[8];
    const float* b3  = (const float*)d_in[9];
    float* out = (float*)d_out;

    char* ws = (char*)d_ws;
    int* prefix          = (int*)ws;                              // 101 ints (512B reserved)
    unsigned short* wt1  = (unsigned short*)(ws + 512);           // 1.5 MB bf16 frag-linear
    unsigned short* wt2  = (unsigned short*)(ws + 512 + 1572864); // 0.75 MB

    prep_kernel<<<576, 256, 0, stream>>>(W1, W2, na, out, prefix, wt1, wt2);
    int nblk = (A_TOTAL + TA - 1) / TA;   // 4167
    angle_main<<<nblk, NTHREADS, 0, stream>>>(r, xyz, ang, b1, b2, W3, b3, out, prefix, wt1, wt2);
}

// Round 5
// 1121.329 us; speedup vs baseline: 2.1566x; 1.0103x over previous
//
#include <hip/hip_runtime.h>

#define A_TOTAL  200000
#define BSEG     100
#define FR_      256
#define DIN_     512
#define H_       256
#define P_       6
#define TA       32
#define NTHREADS 512

typedef float f32x4  __attribute__((ext_vector_type(4)));
typedef short bf16x8 __attribute__((ext_vector_type(8)));

__device__ __forceinline__ unsigned short f2bf(float x) {
    union { float f; unsigned int u; } c; c.f = x;
    unsigned int u = c.u;
    return (unsigned short)((u + 0x7fffu + ((u >> 16) & 1u)) >> 16);
}
__device__ __forceinline__ float fast_tanh(float x) {
    float e = __expf(2.f * x);
    return 1.f - 2.f / (e + 1.f);
}
// XOR swizzle: rows are bank-aligned (1024B/512B stride); XOR row into the
// 16B-slot bits so a 16-row ds_read_b128 column-slice is <=2-way.
__device__ __forceinline__ int swzNI(int row, int kb) { return row * 1024 + (kb ^ ((row & 7) << 4)); }
__device__ __forceinline__ int swzH (int row, int kb) { return row * 512  + (kb ^ ((row & 7) << 4)); }

__device__ __forceinline__ f32x4 mfma16(bf16x8 a, bf16x8 b, f32x4 c) {
    return __builtin_amdgcn_mfma_f32_16x16x32_bf16(a, b, c, 0, 0, 0);
}

// ---------------------------------------------------------------------------
// Prep: W1/W2 -> bf16 fragment-linear layout; prefix-sum num_angles; zero out.
// B-frag for 16x16x32: lane l holds B[k = s*32 + 8*(l>>4) + j][n = nt*16 + (l&15)]
// stored as wt[p][s][nt][l][j] (16B per lane -> coalesced 1KB wave loads).
// ---------------------------------------------------------------------------
__global__ void prep_kernel(const float* __restrict__ W1, const float* __restrict__ W2,
                            const int* __restrict__ num_angles, float* __restrict__ out,
                            int* __restrict__ prefix,
                            unsigned short* __restrict__ wt1, unsigned short* __restrict__ wt2) {
    int tt = blockIdx.x * blockDim.x + threadIdx.x;
    if (blockIdx.x == 0) {
        if (threadIdx.x < BSEG) out[threadIdx.x] = 0.f;
        if (threadIdx.x == 0) {
            int acc = 0; prefix[0] = 0;
            for (int i = 0; i < BSEG; ++i) { acc += num_angles[i]; prefix[i + 1] = acc; }
        }
    }
    if (tt < 98304) {                       // W1: 6 p * 16 s * 16 nt * 64 lanes
        int l  = tt & 63;
        int nt = (tt >> 6) & 15;
        int s  = (tt >> 10) & 15;
        int p  = tt >> 14;
        int k  = s * 32 + 8 * (l >> 4);
        int n  = nt * 16 + (l & 15);
        const float* src = W1 + ((size_t)p * DIN_ + k) * H_ + n;
        unsigned short tmp[8];
#pragma unroll
        for (int j = 0; j < 8; ++j) tmp[j] = f2bf(src[(size_t)j * H_]);
        *reinterpret_cast<uint4*>(wt1 + (size_t)tt * 8) = *reinterpret_cast<uint4*>(tmp);
    } else if (tt < 98304 + 49152) {        // W2: 6 p * 8 s * 16 nt * 64 lanes
        int t2 = tt - 98304;
        int l  = t2 & 63;
        int nt = (t2 >> 6) & 15;
        int s  = (t2 >> 10) & 7;
        int p  = t2 >> 13;
        int k  = s * 32 + 8 * (l >> 4);
        int n  = nt * 16 + (l & 15);
        const float* src = W2 + ((size_t)p * H_ + k) * H_ + n;
        unsigned short tmp[8];
#pragma unroll
        for (int j = 0; j < 8; ++j) tmp[j] = f2bf(src[(size_t)j * H_]);
        *reinterpret_cast<uint4*>(wt2 + (size_t)t2 * 8) = *reinterpret_cast<uint4*>(tmp);
    }
}

// ---------------------------------------------------------------------------
// Main fused kernel: TA=32 angles/block, 8 waves, each wave = 32 rows x 32 cols.
// LDS ~49 KB -> 3 blocks/CU. 2 barriers per p. 200000 % 32 == 0: no tail.
// ---------------------------------------------------------------------------
__global__ __launch_bounds__(NTHREADS, 6)
void angle_main(const float* __restrict__ r, const float* __restrict__ xyz,
                const int* __restrict__ ang,
                const float* __restrict__ b1, const float* __restrict__ b2,
                const float* __restrict__ W3, const float* __restrict__ b3,
                float* __restrict__ out, const int* __restrict__ prefix,
                const unsigned short* __restrict__ wt1, const unsigned short* __restrict__ wt2) {
    __shared__ unsigned short sNI[TA * DIN_];   // 32 KB, swizzled bf16 node_input
    __shared__ unsigned short sH[TA * H_];      // 16 KB, swizzled bf16 H1
    __shared__ float sOut[P_ * TA];             // per-p MLP scalar outputs (atomic acc)
    __shared__ float sSeg[BSEG];                // per-block segment bins

    const int tid  = threadIdx.x;
    const int lane = tid & 63;
    const int w    = tid >> 6;     // wave id: owns cols [w*32, w*32+32)
    const int aB   = blockIdx.x * TA;
    char* cNI = (char*)sNI;
    char* cH  = (char*)sH;

    if (tid < P_ * TA) sOut[tid] = 0.f;
    if (tid < BSEG)    sSeg[tid] = 0.f;

    // ---- gather node_input = [r[a0]+r[a2], r[a1]] -> LDS bf16 (swizzled) ----
#pragma unroll
    for (int it = 0; it < 4; ++it) {
        int c   = it * NTHREADS + tid;       // 2048 chunks of 8 elems
        int row = c >> 6;
        int k0  = (c & 63) * 8;
        int a   = aB + row;
        int i0 = ang[3 * a], i1 = ang[3 * a + 1], i2 = ang[3 * a + 2];
        float v[8];
        if (k0 < FR_) {
            const float4* p0 = (const float4*)(r + (size_t)i0 * FR_ + k0);
            const float4* p2 = (const float4*)(r + (size_t)i2 * FR_ + k0);
            float4 x0 = p0[0], x1 = p0[1], y0 = p2[0], y1 = p2[1];
            v[0] = x0.x + y0.x; v[1] = x0.y + y0.y; v[2] = x0.z + y0.z; v[3] = x0.w + y0.w;
            v[4] = x1.x + y1.x; v[5] = x1.y + y1.y; v[6] = x1.z + y1.z; v[7] = x1.w + y1.w;
        } else {
            const float4* p1 = (const float4*)(r + (size_t)i1 * FR_ + (k0 - FR_));
            float4 x0 = p1[0], x1 = p1[1];
            v[0] = x0.x; v[1] = x0.y; v[2] = x0.z; v[3] = x0.w;
            v[4] = x1.x; v[5] = x1.y; v[6] = x1.z; v[7] = x1.w;
        }
        unsigned short u[8];
#pragma unroll
        for (int j = 0; j < 8; ++j) u[j] = f2bf(v[j]);
        *reinterpret_cast<uint4*>(cNI + swzNI(row, k0 * 2)) = *reinterpret_cast<uint4*>(u);
    }
    __syncthreads();

    for (int p = 0; p < P_; ++p) {
        // ---------------- layer 1: [32x512] @ [512x256], wave cols w*32.. ----
        f32x4 acc[2][2];
#pragma unroll
        for (int mt = 0; mt < 2; ++mt)
#pragma unroll
            for (int nt = 0; nt < 2; ++nt) acc[mt][nt] = (f32x4){0.f, 0.f, 0.f, 0.f};
        const unsigned short* B1 = wt1 + (size_t)p * 131072;
#pragma unroll
        for (int s = 0; s < 16; ++s) {
            int kb = (s * 32 + 8 * (lane >> 4)) * 2;
            bf16x8 af[2];
#pragma unroll
            for (int mt = 0; mt < 2; ++mt)
                af[mt] = *(const bf16x8*)(cNI + swzNI(mt * 16 + (lane & 15), kb));
#pragma unroll
            for (int nt = 0; nt < 2; ++nt) {
                int ntile = w * 2 + nt;
                bf16x8 bfr = *(const bf16x8*)(B1 + (size_t)((s * 16 + ntile) * 64 + lane) * 8);
#pragma unroll
                for (int mt = 0; mt < 2; ++mt) acc[mt][nt] = mfma16(af[mt], bfr, acc[mt][nt]);
            }
        }
        {   // bias + tanh + write H1 (D layout: row = 4*(l>>4)+i, col = l&15)
            const float* bp = b1 + p * H_;
#pragma unroll
            for (int nt = 0; nt < 2; ++nt) {
                int col = w * 32 + nt * 16 + (lane & 15);
                float bias = bp[col];
#pragma unroll
                for (int mt = 0; mt < 2; ++mt) {
                    int rb = mt * 16 + 4 * (lane >> 4);
#pragma unroll
                    for (int i = 0; i < 4; ++i) {
                        float hx = fast_tanh(acc[mt][nt][i] + bias);
                        *(unsigned short*)(cH + swzH(rb + i, col * 2)) = f2bf(hx);
                    }
                }
            }
        }
        __syncthreads();

        // ---------------- layer 2: [32x256] @ [256x256] ----------------
        f32x4 acc2[2][2];
#pragma unroll
        for (int mt = 0; mt < 2; ++mt)
#pragma unroll
            for (int nt = 0; nt < 2; ++nt) acc2[mt][nt] = (f32x4){0.f, 0.f, 0.f, 0.f};
        const unsigned short* B2 = wt2 + (size_t)p * 65536;
#pragma unroll
        for (int s = 0; s < 8; ++s) {
            int kb = (s * 32 + 8 * (lane >> 4)) * 2;
            bf16x8 af[2];
#pragma unroll
            for (int mt = 0; mt < 2; ++mt)
                af[mt] = *(const bf16x8*)(cH + swzH(mt * 16 + (lane & 15), kb));
#pragma unroll
            for (int nt = 0; nt < 2; ++nt) {
                int ntile = w * 2 + nt;
                bf16x8 bfr = *(const bf16x8*)(B2 + (size_t)((s * 16 + ntile) * 64 + lane) * 8);
#pragma unroll
                for (int mt = 0; mt < 2; ++mt) acc2[mt][nt] = mfma16(af[mt], bfr, acc2[mt][nt]);
            }
        }

        // ---- layer 3 from registers: out[p][a] = sum_n tanh(acc2+b2)[a][n]*w3[n] ----
        {
            const float* bp2 = b2 + p * H_;
            const float* w3p = W3 + p * H_;
            float prt[8];
#pragma unroll
            for (int k = 0; k < 8; ++k) prt[k] = 0.f;
#pragma unroll
            for (int nt = 0; nt < 2; ++nt) {
                int col = w * 32 + nt * 16 + (lane & 15);
                float bias = bp2[col];
                float wv   = w3p[col];
#pragma unroll
                for (int mt = 0; mt < 2; ++mt)
#pragma unroll
                    for (int i = 0; i < 4; ++i)
                        prt[mt * 4 + i] += fast_tanh(acc2[mt][nt][i] + bias) * wv;
            }
#pragma unroll
            for (int st = 1; st < 16; st <<= 1)
#pragma unroll
                for (int k = 0; k < 8; ++k) prt[k] += __shfl_xor(prt[k], st);
            if ((lane & 15) == 0) {
                int rg = 4 * (lane >> 4);
#pragma unroll
                for (int mt = 0; mt < 2; ++mt)
#pragma unroll
                    for (int i = 0; i < 4; ++i)
                        atomicAdd(&sOut[p * TA + mt * 16 + rg + i], prt[mt * 4 + i]);
            }
        }
        __syncthreads();   // sH reads done (next p overwrites) + sOut[p] visible
    }

    // ---------------- geometry + energy + segment sum ----------------
    if (tid < TA) {
        int a = aB + tid;
        int i0 = ang[3 * a], i1 = ang[3 * a + 1], i2 = ang[3 * a + 2];
        float ax = xyz[3 * i0], ay = xyz[3 * i0 + 1], az = xyz[3 * i0 + 2];
        float bx = xyz[3 * i1], by = xyz[3 * i1 + 1], bz = xyz[3 * i1 + 2];
        float cx = xyz[3 * i2], cy = xyz[3 * i2 + 1], cz = xyz[3 * i2 + 2];
        float v1x = bx - ax, v1y = by - ay, v1z = bz - az;
        float v2x = cx - bx, v2y = cy - by, v2z = cz - bz;
        float dot = -(v1x * v2x + v1y * v2y + v1z * v2z);
        float n1  = v1x * v1x + v1y * v1y + v1z * v1z;
        float n2  = v2x * v2x + v2y * v2y + v2z * v2z;
        float ct  = dot / sqrtf(n1 * n2);
        float th  = acosf(ct / 1.000001f);

        float o0 = sOut[0 * TA + tid] + b3[0], o1 = sOut[1 * TA + tid] + b3[1];
        float o2 = sOut[2 * TA + tid] + b3[2], o3 = sOut[3 * TA + tid] + b3[3];
        float o4 = sOut[4 * TA + tid] + b3[4], o5 = sOut[5 * TA + tid] + b3[5];
        float t0h = (1.38243827f + o0); t0h *= t0h;       // (sqrt(109.5*pi/180)+o0)^2
        float kh  = (3.16227766f + o1); kh  *= kh;        // (sqrt(10)+o1)^2
        float d   = th - t0h;
        float E   = 0.5f * kh * d * d;
        float t0c = o2 * o2, kc = o3 * o3;
        float dc  = th - t0c;
        E += 0.5f * kc * dc * dc * dc;
        float t0q = o4 * o4, kq = o5 * o5;
        float dq  = th - t0q;
        E += 0.5f * kq * dq * dq * dq * dq;

        int lo = 0, hi = BSEG - 1;                        // last s with prefix[s] <= a
        while (lo < hi) { int mid = (lo + hi + 1) >> 1; if (prefix[mid] <= a) lo = mid; else hi = mid - 1; }
        atomicAdd(&sSeg[lo], E);
    }
    __syncthreads();
    if (tid < BSEG) {
        float v = sSeg[tid];
        if (v != 0.f) atomicAdd(out + tid, v);
    }
}

extern "C" void kernel_launch(void* const* d_in, const int* in_sizes, int n_in,
                              void* d_out, int out_size, void* d_ws, size_t ws_size,
                              hipStream_t stream) {
    const float* r   = (const float*)d_in[0];
    const float* xyz = (const float*)d_in[1];
    const int*   ang = (const int*)d_in[2];
    const int*   na  = (const int*)d_in[3];
    const float* W1  = (const float*)d_in[4];
    const float* b1  = (const float*)d_in[5];
    const float* W2  = (const float*)d_in[6];
    const float* b2  = (const float*)d_in[7];
    const float* W3  = (const float*)d_in[8];
    const float* b3  = (const float*)d_in[9];
    float* out = (float*)d_out;

    char* ws = (char*)d_ws;
    int* prefix          = (int*)ws;                              // 101 ints (512B reserved)
    unsigned short* wt1  = (unsigned short*)(ws + 512);           // 1.5 MB bf16 frag-linear
    unsigned short* wt2  = (unsigned short*)(ws + 512 + 1572864); // 0.75 MB

    prep_kernel<<<576, 256, 0, stream>>>(W1, W2, na, out, prefix, wt1, wt2);
    int nblk = A_TOTAL / TA;   // 6250, exact
    angle_main<<<nblk, NTHREADS, 0, stream>>>(r, xyz, ang, b1, b2, W3, b3, out, prefix, wt1, wt2);
}

// Round 6
// 784.510 us; speedup vs baseline: 3.0825x; 1.4293x over previous
//
#include <hip/hip_runtime.h>
#include <hip/hip_bf16.h>

#define A_TOTAL  200000
#define BSEG     100
#define FR_      256
#define DIN_     512
#define H_       256
#define P_       6
#define TA       32
#define NTHREADS 512

#define SNI_STRIDE 1040   // 512 bf16 = 1024B + 16B pad -> bank drift 4/row, <=2-way
#define SH_STRIDE  528    // 256 bf16 = 512B + 16B pad

typedef float f32x4  __attribute__((ext_vector_type(4)));
typedef short bf16x8 __attribute__((ext_vector_type(8)));

__device__ __forceinline__ unsigned short f2bf(float x) {
    union { float f; unsigned int u; } c; c.f = x;
    unsigned int u = c.u;
    return (unsigned short)((u + 0x7fffu + ((u >> 16) & 1u)) >> 16);
}
__device__ __forceinline__ unsigned int pk2(float a, float b) {   // v_cvt_pk_bf16_f32
    union { __hip_bfloat162 h2; unsigned int u; } c;
    c.h2 = __float22bfloat162_rn(float2{a, b});
    return c.u;
}
__device__ __forceinline__ float fast_tanh(float x) {
    float e = __expf(2.f * x);
    return 1.f - 2.f / (e + 1.f);
}
__device__ __forceinline__ f32x4 mfma16(bf16x8 a, bf16x8 b, f32x4 c) {
    return __builtin_amdgcn_mfma_f32_16x16x32_bf16(a, b, c, 0, 0, 0);
}

// ---------------------------------------------------------------------------
// Prep: W1/W2 -> bf16 fragment-linear layout; prefix-sum num_angles; zero out.
// B-frag for 16x16x32: lane l holds B[k = s*32 + 8*(l>>4) + j][n = nt*16 + (l&15)]
// stored as wt[p][s][nt][l][j] (16B per lane -> coalesced 1KB wave loads).
// ---------------------------------------------------------------------------
__global__ void prep_kernel(const float* __restrict__ W1, const float* __restrict__ W2,
                            const int* __restrict__ num_angles, float* __restrict__ out,
                            int* __restrict__ prefix,
                            unsigned short* __restrict__ wt1, unsigned short* __restrict__ wt2) {
    int tt = blockIdx.x * blockDim.x + threadIdx.x;
    if (blockIdx.x == 0) {
        if (threadIdx.x < BSEG) out[threadIdx.x] = 0.f;
        if (threadIdx.x == 0) {
            int acc = 0; prefix[0] = 0;
            for (int i = 0; i < BSEG; ++i) { acc += num_angles[i]; prefix[i + 1] = acc; }
        }
    }
    if (tt < 98304) {                       // W1: 6 p * 16 s * 16 nt * 64 lanes
        int l  = tt & 63;
        int nt = (tt >> 6) & 15;
        int s  = (tt >> 10) & 15;
        int p  = tt >> 14;
        int k  = s * 32 + 8 * (l >> 4);
        int n  = nt * 16 + (l & 15);
        const float* src = W1 + ((size_t)p * DIN_ + k) * H_ + n;
        unsigned short tmp[8];
#pragma unroll
        for (int j = 0; j < 8; ++j) tmp[j] = f2bf(src[(size_t)j * H_]);
        *reinterpret_cast<uint4*>(wt1 + (size_t)tt * 8) = *reinterpret_cast<uint4*>(tmp);
    } else if (tt < 98304 + 49152) {        // W2: 6 p * 8 s * 16 nt * 64 lanes
        int t2 = tt - 98304;
        int l  = t2 & 63;
        int nt = (t2 >> 6) & 15;
        int s  = (t2 >> 10) & 7;
        int p  = t2 >> 13;
        int k  = s * 32 + 8 * (l >> 4);
        int n  = nt * 16 + (l & 15);
        const float* src = W2 + ((size_t)p * H_ + k) * H_ + n;
        unsigned short tmp[8];
#pragma unroll
        for (int j = 0; j < 8; ++j) tmp[j] = f2bf(src[(size_t)j * H_]);
        *reinterpret_cast<uint4*>(wt2 + (size_t)t2 * 8) = *reinterpret_cast<uint4*>(tmp);
    }
}

// ---------------------------------------------------------------------------
// Main fused kernel: TA=32 angles/block, 8 waves, wave = 32 rows x 32 cols.
// Padded-stride LDS (no XOR): all s-loop LDS addresses fold to base+imm.
// ---------------------------------------------------------------------------
__global__ __launch_bounds__(NTHREADS, 4)
void angle_main(const float* __restrict__ r, const float* __restrict__ xyz,
                const int* __restrict__ ang,
                const float* __restrict__ b1, const float* __restrict__ b2,
                const float* __restrict__ W3, const float* __restrict__ b3,
                float* __restrict__ out, const int* __restrict__ prefix,
                const unsigned short* __restrict__ wt1, const unsigned short* __restrict__ wt2) {
    __shared__ __align__(16) char cNI[TA * SNI_STRIDE];  // 33280 B
    __shared__ __align__(16) char cH[TA * SH_STRIDE];    // 16896 B
    __shared__ float sOut[P_ * TA];
    __shared__ float sSeg[BSEG];

    const int tid  = threadIdx.x;
    const int lane = tid & 63;
    const int w    = tid >> 6;        // wave id: owns cols [w*32, w*32+32)
    const int aB   = blockIdx.x * TA;
    const int rA   = lane & 15;       // A-frag row within 16-tile
    const int q16  = 16 * (lane >> 4);// A-frag k-subgroup byte offset

    if (tid < P_ * TA) sOut[tid] = 0.f;
    if (tid < BSEG)    sSeg[tid] = 0.f;

    // ---- gather node_input = [r[a0]+r[a2], r[a1]] -> LDS bf16 ----
#pragma unroll
    for (int it = 0; it < 4; ++it) {
        int c   = it * NTHREADS + tid;       // 2048 chunks of 8 elems
        int row = c >> 6;
        int k0  = (c & 63) * 8;
        int a   = aB + row;
        int i0 = ang[3 * a], i1 = ang[3 * a + 1], i2 = ang[3 * a + 2];
        float v[8];
        if (k0 < FR_) {
            const float4* p0 = (const float4*)(r + (size_t)i0 * FR_ + k0);
            const float4* p2 = (const float4*)(r + (size_t)i2 * FR_ + k0);
            float4 x0 = p0[0], x1 = p0[1], y0 = p2[0], y1 = p2[1];
            v[0] = x0.x + y0.x; v[1] = x0.y + y0.y; v[2] = x0.z + y0.z; v[3] = x0.w + y0.w;
            v[4] = x1.x + y1.x; v[5] = x1.y + y1.y; v[6] = x1.z + y1.z; v[7] = x1.w + y1.w;
        } else {
            const float4* p1 = (const float4*)(r + (size_t)i1 * FR_ + (k0 - FR_));
            float4 x0 = p1[0], x1 = p1[1];
            v[0] = x0.x; v[1] = x0.y; v[2] = x0.z; v[3] = x0.w;
            v[4] = x1.x; v[5] = x1.y; v[6] = x1.z; v[7] = x1.w;
        }
        uint4 pk;
        pk.x = pk2(v[0], v[1]); pk.y = pk2(v[2], v[3]);
        pk.z = pk2(v[4], v[5]); pk.w = pk2(v[6], v[7]);
        *reinterpret_cast<uint4*>(cNI + row * SNI_STRIDE + k0 * 2) = pk;
    }
    __syncthreads();

    for (int p = 0; p < P_; ++p) {
        // ---------------- layer 1: [32x512] @ [512x256], wave cols w*32.. ----
        f32x4 acc[2][2];
#pragma unroll
        for (int mt = 0; mt < 2; ++mt)
#pragma unroll
            for (int nt = 0; nt < 2; ++nt) acc[mt][nt] = (f32x4){0.f, 0.f, 0.f, 0.f};
        {
            const char* a0b = cNI + rA * SNI_STRIDE + q16;
            const char* a1b = a0b + 16 * SNI_STRIDE;
            const unsigned short* bp0 = wt1 + (size_t)p * 131072 + (size_t)((w * 2 + 0) * 64 + lane) * 8;
            const unsigned short* bp1 = bp0 + 512;   // next ntile: 64 lanes * 8
#pragma unroll
            for (int s = 0; s < 16; ++s) {
                bf16x8 a0 = *(const bf16x8*)(a0b + 64 * s);
                bf16x8 a1 = *(const bf16x8*)(a1b + 64 * s);
                bf16x8 b0 = *(const bf16x8*)(bp0 + (size_t)s * 8192);
                bf16x8 b1 = *(const bf16x8*)(bp1 + (size_t)s * 8192);
                acc[0][0] = mfma16(a0, b0, acc[0][0]);
                acc[1][0] = mfma16(a1, b0, acc[1][0]);
                acc[0][1] = mfma16(a0, b1, acc[0][1]);
                acc[1][1] = mfma16(a1, b1, acc[1][1]);
            }
        }
        {   // bias + tanh + packed bf16 -> cH (D layout: row = 4*(l>>4)+i, col = l&15)
            const float* bp = b1 + p * H_;
#pragma unroll
            for (int nt = 0; nt < 2; ++nt) {
                int col = w * 32 + nt * 16 + rA;
                float bias = bp[col];
#pragma unroll
                for (int mt = 0; mt < 2; ++mt) {
                    float t0 = fast_tanh(acc[mt][nt][0] + bias);
                    float t1 = fast_tanh(acc[mt][nt][1] + bias);
                    float t2 = fast_tanh(acc[mt][nt][2] + bias);
                    float t3 = fast_tanh(acc[mt][nt][3] + bias);
                    unsigned int u01 = pk2(t0, t1);
                    unsigned int u23 = pk2(t2, t3);
                    char* base = cH + (mt * 16 + (lane >> 4) * 4) * SH_STRIDE + col * 2;
                    *(unsigned short*)(base)                 = (unsigned short)(u01 & 0xffff);
                    *(unsigned short*)(base + SH_STRIDE)     = (unsigned short)(u01 >> 16);
                    *(unsigned short*)(base + 2 * SH_STRIDE) = (unsigned short)(u23 & 0xffff);
                    *(unsigned short*)(base + 3 * SH_STRIDE) = (unsigned short)(u23 >> 16);
                }
            }
        }
        __syncthreads();

        // ---------------- layer 2: [32x256] @ [256x256] ----------------
        f32x4 acc2[2][2];
#pragma unroll
        for (int mt = 0; mt < 2; ++mt)
#pragma unroll
            for (int nt = 0; nt < 2; ++nt) acc2[mt][nt] = (f32x4){0.f, 0.f, 0.f, 0.f};
        {
            const char* a0b = cH + rA * SH_STRIDE + q16;
            const char* a1b = a0b + 16 * SH_STRIDE;
            const unsigned short* bp0 = wt2 + (size_t)p * 65536 + (size_t)((w * 2 + 0) * 64 + lane) * 8;
            const unsigned short* bp1 = bp0 + 512;
#pragma unroll
            for (int s = 0; s < 8; ++s) {
                bf16x8 a0 = *(const bf16x8*)(a0b + 64 * s);
                bf16x8 a1 = *(const bf16x8*)(a1b + 64 * s);
                bf16x8 b0 = *(const bf16x8*)(bp0 + (size_t)s * 8192);
                bf16x8 b1 = *(const bf16x8*)(bp1 + (size_t)s * 8192);
                acc2[0][0] = mfma16(a0, b0, acc2[0][0]);
                acc2[1][0] = mfma16(a1, b0, acc2[1][0]);
                acc2[0][1] = mfma16(a0, b1, acc2[0][1]);
                acc2[1][1] = mfma16(a1, b1, acc2[1][1]);
            }
        }

        // ---- layer 3 from registers: out[p][a] = sum_n tanh(acc2+b2)[a][n]*w3[n] ----
        {
            const float* bp2 = b2 + p * H_;
            const float* w3p = W3 + p * H_;
            float prt[8];
#pragma unroll
            for (int k = 0; k < 8; ++k) prt[k] = 0.f;
#pragma unroll
            for (int nt = 0; nt < 2; ++nt) {
                int col = w * 32 + nt * 16 + rA;
                float bias = bp2[col];
                float wv   = w3p[col];
#pragma unroll
                for (int mt = 0; mt < 2; ++mt)
#pragma unroll
                    for (int i = 0; i < 4; ++i)
                        prt[mt * 4 + i] += fast_tanh(acc2[mt][nt][i] + bias) * wv;
            }
#pragma unroll
            for (int st = 1; st < 16; st <<= 1)
#pragma unroll
                for (int k = 0; k < 8; ++k) prt[k] += __shfl_xor(prt[k], st);
            if (rA == 0) {
                int rg = (lane >> 4) * 4;
#pragma unroll
                for (int mt = 0; mt < 2; ++mt)
#pragma unroll
                    for (int i = 0; i < 4; ++i)
                        atomicAdd(&sOut[p * TA + mt * 16 + rg + i], prt[mt * 4 + i]);
            }
        }
        __syncthreads();   // cH reads done (next p overwrites) + sOut[p] visible
    }

    // ---------------- geometry + energy + segment sum ----------------
    if (tid < TA) {
        int a = aB + tid;
        int i0 = ang[3 * a], i1 = ang[3 * a + 1], i2 = ang[3 * a + 2];
        float ax = xyz[3 * i0], ay = xyz[3 * i0 + 1], az = xyz[3 * i0 + 2];
        float bx = xyz[3 * i1], by = xyz[3 * i1 + 1], bz = xyz[3 * i1 + 2];
        float cx = xyz[3 * i2], cy = xyz[3 * i2 + 1], cz = xyz[3 * i2 + 2];
        float v1x = bx - ax, v1y = by - ay, v1z = bz - az;
        float v2x = cx - bx, v2y = cy - by, v2z = cz - bz;
        float dot = -(v1x * v2x + v1y * v2y + v1z * v2z);
        float n1  = v1x * v1x + v1y * v1y + v1z * v1z;
        float n2  = v2x * v2x + v2y * v2y + v2z * v2z;
        float ct  = dot / sqrtf(n1 * n2);
        float th  = acosf(ct / 1.000001f);

        float o0 = sOut[0 * TA + tid] + b3[0], o1 = sOut[1 * TA + tid] + b3[1];
        float o2 = sOut[2 * TA + tid] + b3[2], o3 = sOut[3 * TA + tid] + b3[3];
        float o4 = sOut[4 * TA + tid] + b3[4], o5 = sOut[5 * TA + tid] + b3[5];
        float t0h = (1.38243827f + o0); t0h *= t0h;       // (sqrt(109.5*pi/180)+o0)^2
        float kh  = (3.16227766f + o1); kh  *= kh;        // (sqrt(10)+o1)^2
        float d   = th - t0h;
        float E   = 0.5f * kh * d * d;
        float t0c = o2 * o2, kc = o3 * o3;
        float dc  = th - t0c;
        E += 0.5f * kc * dc * dc * dc;
        float t0q = o4 * o4, kq = o5 * o5;
        float dq  = th - t0q;
        E += 0.5f * kq * dq * dq * dq * dq;

        int lo = 0, hi = BSEG - 1;                        // last s with prefix[s] <= a
        while (lo < hi) { int mid = (lo + hi + 1) >> 1; if (prefix[mid] <= a) lo = mid; else hi = mid - 1; }
        atomicAdd(&sSeg[lo], E);
    }
    __syncthreads();
    if (tid < BSEG) {
        float v = sSeg[tid];
        if (v != 0.f) atomicAdd(out + tid, v);
    }
}

extern "C" void kernel_launch(void* const* d_in, const int* in_sizes, int n_in,
                              void* d_out, int out_size, void* d_ws, size_t ws_size,
                              hipStream_t stream) {
    const float* r   = (const float*)d_in[0];
    const float* xyz = (const float*)d_in[1];
    const int*   ang = (const int*)d_in[2];
    const int*   na  = (const int*)d_in[3];
    const float* W1  = (const float*)d_in[4];
    const float* b1  = (const float*)d_in[5];
    const float* W2  = (const float*)d_in[6];
    const float* b2  = (const float*)d_in[7];
    const float* W3  = (const float*)d_in[8];
    const float* b3  = (const float*)d_in[9];
    float* out = (float*)d_out;

    char* ws = (char*)d_ws;
    int* prefix          = (int*)ws;                              // 101 ints (512B reserved)
    unsigned short* wt1  = (unsigned short*)(ws + 512);           // 1.5 MB bf16 frag-linear
    unsigned short* wt2  = (unsigned short*)(ws + 512 + 1572864); // 0.75 MB

    prep_kernel<<<576, 256, 0, stream>>>(W1, W2, na, out, prefix, wt1, wt2);
    int nblk = A_TOTAL / TA;   // 6250, exact
    angle_main<<<nblk, NTHREADS, 0, stream>>>(r, xyz, ang, b1, b2, W3, b3, out, prefix, wt1, wt2);
}

// Round 7
// 668.573 us; speedup vs baseline: 3.6171x; 1.1734x over previous
//
#include <hip/hip_runtime.h>
#include <hip/hip_bf16.h>

#define A_TOTAL  200000
#define BSEG     100
#define FR_      256
#define DIN_     512
#define H_       256
#define P_       6
#define TA       32
#define NTHREADS 512

#define SNI_STRIDE 1040   // 512 bf16 = 1024B + 16B pad -> bank drift 4/row, <=2-way
#define SH_STRIDE  528    // 256 bf16 = 512B + 16B pad

typedef float f32x4  __attribute__((ext_vector_type(4)));
typedef short bf16x8 __attribute__((ext_vector_type(8)));

__device__ __forceinline__ unsigned short f2bf(float x) {
    union { float f; unsigned int u; } c; c.f = x;
    unsigned int u = c.u;
    return (unsigned short)((u + 0x7fffu + ((u >> 16) & 1u)) >> 16);
}
__device__ __forceinline__ unsigned int pk2(float a, float b) {   // v_cvt_pk_bf16_f32
    union { __hip_bfloat162 h2; unsigned int u; } c;
    c.h2 = __float22bfloat162_rn(float2{a, b});
    return c.u;
}
// 5-op tanh: mul, v_exp, add, v_rcp, fma. rcp is 1-ulp -> fine for bf16 output.
__device__ __forceinline__ float fast_tanh(float x) {
    float e = __expf(x + x);
    float r = __builtin_amdgcn_rcpf(e + 1.f);
    return 1.f - (r + r);
}
__device__ __forceinline__ f32x4 mfma16(bf16x8 a, bf16x8 b, f32x4 c) {
    return __builtin_amdgcn_mfma_f32_16x16x32_bf16(a, b, c, 0, 0, 0);
}

// ---------------------------------------------------------------------------
// Prep: W1/W2 -> bf16 fragment-linear layout; prefix-sum num_angles; zero out.
// B-frag for 16x16x32: lane l holds B[k = s*32 + 8*(l>>4) + j][n = nt*16 + (l&15)]
// stored as wt[p][s][nt][l][j] (16B per lane -> coalesced 1KB wave loads).
// ---------------------------------------------------------------------------
__global__ void prep_kernel(const float* __restrict__ W1, const float* __restrict__ W2,
                            const int* __restrict__ num_angles, float* __restrict__ out,
                            int* __restrict__ prefix,
                            unsigned short* __restrict__ wt1, unsigned short* __restrict__ wt2) {
    int tt = blockIdx.x * blockDim.x + threadIdx.x;
    if (blockIdx.x == 0) {
        if (threadIdx.x < BSEG) out[threadIdx.x] = 0.f;
        if (threadIdx.x == 0) {
            int acc = 0; prefix[0] = 0;
            for (int i = 0; i < BSEG; ++i) { acc += num_angles[i]; prefix[i + 1] = acc; }
        }
    }
    if (tt < 98304) {                       // W1: 6 p * 16 s * 16 nt * 64 lanes
        int l  = tt & 63;
        int nt = (tt >> 6) & 15;
        int s  = (tt >> 10) & 15;
        int p  = tt >> 14;
        int k  = s * 32 + 8 * (l >> 4);
        int n  = nt * 16 + (l & 15);
        const float* src = W1 + ((size_t)p * DIN_ + k) * H_ + n;
        unsigned short tmp[8];
#pragma unroll
        for (int j = 0; j < 8; ++j) tmp[j] = f2bf(src[(size_t)j * H_]);
        *reinterpret_cast<uint4*>(wt1 + (size_t)tt * 8) = *reinterpret_cast<uint4*>(tmp);
    } else if (tt < 98304 + 49152) {        // W2: 6 p * 8 s * 16 nt * 64 lanes
        int t2 = tt - 98304;
        int l  = t2 & 63;
        int nt = (t2 >> 6) & 15;
        int s  = (t2 >> 10) & 7;
        int p  = t2 >> 13;
        int k  = s * 32 + 8 * (l >> 4);
        int n  = nt * 16 + (l & 15);
        const float* src = W2 + ((size_t)p * H_ + k) * H_ + n;
        unsigned short tmp[8];
#pragma unroll
        for (int j = 0; j < 8; ++j) tmp[j] = f2bf(src[(size_t)j * H_]);
        *reinterpret_cast<uint4*>(wt2 + (size_t)t2 * 8) = *reinterpret_cast<uint4*>(tmp);
    }
}

// ---------------------------------------------------------------------------
// Main fused kernel: TA=32 angles/block, 8 waves, wave = 32 rows x 32 cols.
// Padded-stride LDS: all s-loop LDS addresses fold to base+imm.
// launch_bounds(512,6): R5 measured 65% occupancy (3 blocks/CU) at this LDS.
// ---------------------------------------------------------------------------
__global__ __launch_bounds__(NTHREADS, 6)
void angle_main(const float* __restrict__ r, const float* __restrict__ xyz,
                const int* __restrict__ ang,
                const float* __restrict__ b1, const float* __restrict__ b2,
                const float* __restrict__ W3, const float* __restrict__ b3,
                float* __restrict__ out, const int* __restrict__ prefix,
                const unsigned short* __restrict__ wt1, const unsigned short* __restrict__ wt2) {
    __shared__ __align__(16) char cNI[TA * SNI_STRIDE];  // 33280 B
    __shared__ __align__(16) char cH[TA * SH_STRIDE];    // 16896 B
    __shared__ float sOut[P_ * TA];
    __shared__ float sSeg[BSEG];

    const int tid  = threadIdx.x;
    const int lane = tid & 63;
    const int w    = tid >> 6;        // wave id: owns cols [w*32, w*32+32)
    const int aB   = blockIdx.x * TA;
    const int rA   = lane & 15;       // A-frag row within 16-tile
    const int q16  = 16 * (lane >> 4);// A-frag k-subgroup byte offset

    if (tid < P_ * TA) sOut[tid] = 0.f;
    if (tid < BSEG)    sSeg[tid] = 0.f;

    // ---- gather node_input = [r[a0]+r[a2], r[a1]] -> LDS bf16 ----
#pragma unroll
    for (int it = 0; it < 4; ++it) {
        int c   = it * NTHREADS + tid;       // 2048 chunks of 8 elems
        int row = c >> 6;
        int k0  = (c & 63) * 8;
        int a   = aB + row;
        int i0 = ang[3 * a], i1 = ang[3 * a + 1], i2 = ang[3 * a + 2];
        float v[8];
        if (k0 < FR_) {
            const float4* p0 = (const float4*)(r + (size_t)i0 * FR_ + k0);
            const float4* p2 = (const float4*)(r + (size_t)i2 * FR_ + k0);
            float4 x0 = p0[0], x1 = p0[1], y0 = p2[0], y1 = p2[1];
            v[0] = x0.x + y0.x; v[1] = x0.y + y0.y; v[2] = x0.z + y0.z; v[3] = x0.w + y0.w;
            v[4] = x1.x + y1.x; v[5] = x1.y + y1.y; v[6] = x1.z + y1.z; v[7] = x1.w + y1.w;
        } else {
            const float4* p1 = (const float4*)(r + (size_t)i1 * FR_ + (k0 - FR_));
            float4 x0 = p1[0], x1 = p1[1];
            v[0] = x0.x; v[1] = x0.y; v[2] = x0.z; v[3] = x0.w;
            v[4] = x1.x; v[5] = x1.y; v[6] = x1.z; v[7] = x1.w;
        }
        uint4 pk;
        pk.x = pk2(v[0], v[1]); pk.y = pk2(v[2], v[3]);
        pk.z = pk2(v[4], v[5]); pk.w = pk2(v[6], v[7]);
        *reinterpret_cast<uint4*>(cNI + row * SNI_STRIDE + k0 * 2) = pk;
    }
    __syncthreads();

    for (int p = 0; p < P_; ++p) {
        // ---------------- layer 1: [32x512] @ [512x256], wave cols w*32.. ----
        // bias folded into MFMA C-init: D-frag regs are 4 rows of one col.
        const float bias10 = b1[p * H_ + w * 32 + rA];
        const float bias11 = b1[p * H_ + w * 32 + 16 + rA];
        f32x4 acc[2][2];
        acc[0][0] = (f32x4){bias10, bias10, bias10, bias10};
        acc[1][0] = acc[0][0];
        acc[0][1] = (f32x4){bias11, bias11, bias11, bias11};
        acc[1][1] = acc[0][1];
        {
            const char* a0b = cNI + rA * SNI_STRIDE + q16;
            const char* a1b = a0b + 16 * SNI_STRIDE;
            const unsigned short* bp0 = wt1 + (size_t)p * 131072 + (size_t)((w * 2 + 0) * 64 + lane) * 8;
            const unsigned short* bp1 = bp0 + 512;   // next ntile: 64 lanes * 8
#pragma unroll
            for (int s = 0; s < 16; ++s) {
                bf16x8 a0 = *(const bf16x8*)(a0b + 64 * s);
                bf16x8 a1 = *(const bf16x8*)(a1b + 64 * s);
                bf16x8 b0 = *(const bf16x8*)(bp0 + (size_t)s * 8192);
                bf16x8 b1v = *(const bf16x8*)(bp1 + (size_t)s * 8192);
                acc[0][0] = mfma16(a0, b0, acc[0][0]);
                acc[1][0] = mfma16(a1, b0, acc[1][0]);
                acc[0][1] = mfma16(a0, b1v, acc[0][1]);
                acc[1][1] = mfma16(a1, b1v, acc[1][1]);
            }
        }
        {   // tanh + packed bf16 -> cH (D layout: row = 4*(l>>4)+i, col = l&15)
#pragma unroll
            for (int nt = 0; nt < 2; ++nt) {
                int col = w * 32 + nt * 16 + rA;
#pragma unroll
                for (int mt = 0; mt < 2; ++mt) {
                    float t0 = fast_tanh(acc[mt][nt][0]);
                    float t1 = fast_tanh(acc[mt][nt][1]);
                    float t2 = fast_tanh(acc[mt][nt][2]);
                    float t3 = fast_tanh(acc[mt][nt][3]);
                    unsigned int u01 = pk2(t0, t1);
                    unsigned int u23 = pk2(t2, t3);
                    char* base = cH + (mt * 16 + (lane >> 4) * 4) * SH_STRIDE + col * 2;
                    *(unsigned short*)(base)                 = (unsigned short)(u01 & 0xffff);
                    *(unsigned short*)(base + SH_STRIDE)     = (unsigned short)(u01 >> 16);
                    *(unsigned short*)(base + 2 * SH_STRIDE) = (unsigned short)(u23 & 0xffff);
                    *(unsigned short*)(base + 3 * SH_STRIDE) = (unsigned short)(u23 >> 16);
                }
            }
        }
        __syncthreads();

        // ---------------- layer 2: [32x256] @ [256x256] ----------------
        const float bias20 = b2[p * H_ + w * 32 + rA];
        const float bias21 = b2[p * H_ + w * 32 + 16 + rA];
        f32x4 acc2[2][2];
        acc2[0][0] = (f32x4){bias20, bias20, bias20, bias20};
        acc2[1][0] = acc2[0][0];
        acc2[0][1] = (f32x4){bias21, bias21, bias21, bias21};
        acc2[1][1] = acc2[0][1];
        {
            const char* a0b = cH + rA * SH_STRIDE + q16;
            const char* a1b = a0b + 16 * SH_STRIDE;
            const unsigned short* bp0 = wt2 + (size_t)p * 65536 + (size_t)((w * 2 + 0) * 64 + lane) * 8;
            const unsigned short* bp1 = bp0 + 512;
#pragma unroll
            for (int s = 0; s < 8; ++s) {
                bf16x8 a0 = *(const bf16x8*)(a0b + 64 * s);
                bf16x8 a1 = *(const bf16x8*)(a1b + 64 * s);
                bf16x8 b0 = *(const bf16x8*)(bp0 + (size_t)s * 8192);
                bf16x8 b1v = *(const bf16x8*)(bp1 + (size_t)s * 8192);
                acc2[0][0] = mfma16(a0, b0, acc2[0][0]);
                acc2[1][0] = mfma16(a1, b0, acc2[1][0]);
                acc2[0][1] = mfma16(a0, b1v, acc2[0][1]);
                acc2[1][1] = mfma16(a1, b1v, acc2[1][1]);
            }
        }

        // ---- layer 3 from registers: out[p][a] = sum_n tanh(acc2)[a][n]*w3[n] ----
        {
            const float* w3p = W3 + p * H_;
            float prt[8];
#pragma unroll
            for (int k = 0; k < 8; ++k) prt[k] = 0.f;
#pragma unroll
            for (int nt = 0; nt < 2; ++nt) {
                float wv = w3p[w * 32 + nt * 16 + rA];
#pragma unroll
                for (int mt = 0; mt < 2; ++mt)
#pragma unroll
                    for (int i = 0; i < 4; ++i)
                        prt[mt * 4 + i] += fast_tanh(acc2[mt][nt][i]) * wv;
            }
#pragma unroll
            for (int st = 1; st < 16; st <<= 1)
#pragma unroll
                for (int k = 0; k < 8; ++k) prt[k] += __shfl_xor(prt[k], st);
            if (rA == 0) {
                int rg = (lane >> 4) * 4;
#pragma unroll
                for (int mt = 0; mt < 2; ++mt)
#pragma unroll
                    for (int i = 0; i < 4; ++i)
                        atomicAdd(&sOut[p * TA + mt * 16 + rg + i], prt[mt * 4 + i]);
            }
        }
        __syncthreads();   // cH reads done (next p overwrites) + sOut[p] visible
    }

    // ---------------- geometry + energy + segment sum ----------------
    if (tid < TA) {
        int a = aB + tid;
        int i0 = ang[3 * a], i1 = ang[3 * a + 1], i2 = ang[3 * a + 2];
        float ax = xyz[3 * i0], ay = xyz[3 * i0 + 1], az = xyz[3 * i0 + 2];
        float bx = xyz[3 * i1], by = xyz[3 * i1 + 1], bz = xyz[3 * i1 + 2];
        float cx = xyz[3 * i2], cy = xyz[3 * i2 + 1], cz = xyz[3 * i2 + 2];
        float v1x = bx - ax, v1y = by - ay, v1z = bz - az;
        float v2x = cx - bx, v2y = cy - by, v2z = cz - bz;
        float dot = -(v1x * v2x + v1y * v2y + v1z * v2z);
        float n1  = v1x * v1x + v1y * v1y + v1z * v1z;
        float n2  = v2x * v2x + v2y * v2y + v2z * v2z;
        float ct  = dot / sqrtf(n1 * n2);
        float th  = acosf(ct / 1.000001f);

        float o0 = sOut[0 * TA + tid] + b3[0], o1 = sOut[1 * TA + tid] + b3[1];
        float o2 = sOut[2 * TA + tid] + b3[2], o3 = sOut[3 * TA + tid] + b3[3];
        float o4 = sOut[4 * TA + tid] + b3[4], o5 = sOut[5 * TA + tid] + b3[5];
        float t0h = (1.38243827f + o0); t0h *= t0h;       // (sqrt(109.5*pi/180)+o0)^2
        float kh  = (3.16227766f + o1); kh  *= kh;        // (sqrt(10)+o1)^2
        float d   = th - t0h;
        float E   = 0.5f * kh * d * d;
        float t0c = o2 * o2, kc = o3 * o3;
        float dc  = th - t0c;
        E += 0.5f * kc * dc * dc * dc;
        float t0q = o4 * o4, kq = o5 * o5;
        float dq  = th - t0q;
        E += 0.5f * kq * dq * dq * dq * dq;

        int lo = 0, hi = BSEG - 1;                        // last s with prefix[s] <= a
        while (lo < hi) { int mid = (lo + hi + 1) >> 1; if (prefix[mid] <= a) lo = mid; else hi = mid - 1; }
        atomicAdd(&sSeg[lo], E);
    }
    __syncthreads();
    if (tid < BSEG) {
        float v = sSeg[tid];
        if (v != 0.f) atomicAdd(out + tid, v);
    }
}

extern "C" void kernel_launch(void* const* d_in, const int* in_sizes, int n_in,
                              void* d_out, int out_size, void* d_ws, size_t ws_size,
                              hipStream_t stream) {
    const float* r   = (const float*)d_in[0];
    const float* xyz = (const float*)d_in[1];
    const int*   ang = (const int*)d_in[2];
    const int*   na  = (const int*)d_in[3];
    const float* W1  = (const float*)d_in[4];
    const float* b1  = (const float*)d_in[5];
    const float* W2  = (const float*)d_in[6];
    const float* b2  = (const float*)d_in[7];
    const float* W3  = (const float*)d_in[8];
    const float* b3  = (const float*)d_in[9];
    float* out = (float*)d_out;

    char* ws = (char*)d_ws;
    int* prefix          = (int*)ws;                              // 101 ints (512B reserved)
    unsigned short* wt1  = (unsigned short*)(ws + 512);           // 1.5 MB bf16 frag-linear
    unsigned short* wt2  = (unsigned short*)(ws + 512 + 1572864); // 0.75 MB

    prep_kernel<<<576, 256, 0, stream>>>(W1, W2, na, out, prefix, wt1, wt2);
    int nblk = A_TOTAL / TA;   // 6250, exact
    angle_main<<<nblk, NTHREADS, 0, stream>>>(r, xyz, ang, b1, b2, W3, b3, out, prefix, wt1, wt2);
}

// Round 8
// 607.606 us; speedup vs baseline: 3.9800x; 1.1003x over previous
//
#include <hip/hip_runtime.h>
#include <hip/hip_bf16.h>

#define A_TOTAL  200000
#define BSEG     100
#define FR_      256
#define DIN_     512
#define H_       256
#define P_       6
#define TA       48
#define NTHREADS 512

#define SNI_STRIDE 1040   // 512 bf16 = 1024B + 16B pad -> bank drift 4/row, <=2-way
#define SH_STRIDE  528    // 256 bf16 = 512B + 16B pad

typedef float f32x4  __attribute__((ext_vector_type(4)));
typedef short bf16x8 __attribute__((ext_vector_type(8)));

__device__ __forceinline__ unsigned short f2bf(float x) {
    union { float f; unsigned int u; } c; c.f = x;
    unsigned int u = c.u;
    return (unsigned short)((u + 0x7fffu + ((u >> 16) & 1u)) >> 16);
}
__device__ __forceinline__ unsigned int pk2(float a, float b) {   // v_cvt_pk_bf16_f32
    union { __hip_bfloat162 h2; unsigned int u; } c;
    c.h2 = __float22bfloat162_rn(float2{a, b});
    return c.u;
}
// 5-op tanh: fma, v_exp, add, v_rcp, fma. rcp is 1-ulp -> fine for bf16 output.
__device__ __forceinline__ float fast_tanh(float x) {
    float e = __expf(x + x);
    float r = __builtin_amdgcn_rcpf(e + 1.f);
    return 1.f - (r + r);
}
__device__ __forceinline__ f32x4 mfma16(bf16x8 a, bf16x8 b, f32x4 c) {
    return __builtin_amdgcn_mfma_f32_16x16x32_bf16(a, b, c, 0, 0, 0);
}

// ---------------------------------------------------------------------------
// Prep: W1/W2 -> bf16 fragment-linear layout; prefix-sum num_angles; zero out.
// B-frag for 16x16x32: lane l holds B[k = s*32 + 8*(l>>4) + j][n = nt*16 + (l&15)]
// stored as wt[p][s][nt][l][j] (16B per lane -> coalesced 1KB wave loads).
// ---------------------------------------------------------------------------
__global__ void prep_kernel(const float* __restrict__ W1, const float* __restrict__ W2,
                            const int* __restrict__ num_angles, float* __restrict__ out,
                            int* __restrict__ prefix,
                            unsigned short* __restrict__ wt1, unsigned short* __restrict__ wt2) {
    int tt = blockIdx.x * blockDim.x + threadIdx.x;
    if (blockIdx.x == 0) {
        if (threadIdx.x < BSEG) out[threadIdx.x] = 0.f;
        if (threadIdx.x == 0) {
            int acc = 0; prefix[0] = 0;
            for (int i = 0; i < BSEG; ++i) { acc += num_angles[i]; prefix[i + 1] = acc; }
        }
    }
    if (tt < 98304) {                       // W1: 6 p * 16 s * 16 nt * 64 lanes
        int l  = tt & 63;
        int nt = (tt >> 6) & 15;
        int s  = (tt >> 10) & 15;
        int p  = tt >> 14;
        int k  = s * 32 + 8 * (l >> 4);
        int n  = nt * 16 + (l & 15);
        const float* src = W1 + ((size_t)p * DIN_ + k) * H_ + n;
        unsigned short tmp[8];
#pragma unroll
        for (int j = 0; j < 8; ++j) tmp[j] = f2bf(src[(size_t)j * H_]);
        *reinterpret_cast<uint4*>(wt1 + (size_t)tt * 8) = *reinterpret_cast<uint4*>(tmp);
    } else if (tt < 98304 + 49152) {        // W2: 6 p * 8 s * 16 nt * 64 lanes
        int t2 = tt - 98304;
        int l  = t2 & 63;
        int nt = (t2 >> 6) & 15;
        int s  = (t2 >> 10) & 7;
        int p  = t2 >> 13;
        int k  = s * 32 + 8 * (l >> 4);
        int n  = nt * 16 + (l & 15);
        const float* src = W2 + ((size_t)p * H_ + k) * H_ + n;
        unsigned short tmp[8];
#pragma unroll
        for (int j = 0; j < 8; ++j) tmp[j] = f2bf(src[(size_t)j * H_]);
        *reinterpret_cast<uint4*>(wt2 + (size_t)t2 * 8) = *reinterpret_cast<uint4*>(tmp);
    }
}

// ---------------------------------------------------------------------------
// Main fused kernel: TA=48 angles/block, 8 waves, wave = 48 rows x 32 cols.
// Ping-pong B-prefetch (depth = 2 s-steps) to hide ~250cy L2 weight latency.
// LDS ~77 KB -> 2 blocks/CU at 4 waves/SIMD (VGPR <= 128).
// ---------------------------------------------------------------------------
__global__ __launch_bounds__(NTHREADS, 4)
void angle_main(const float* __restrict__ r, const float* __restrict__ xyz,
                const int* __restrict__ ang,
                const float* __restrict__ b1, const float* __restrict__ b2,
                const float* __restrict__ W3, const float* __restrict__ b3,
                float* __restrict__ out, const int* __restrict__ prefix,
                const unsigned short* __restrict__ wt1, const unsigned short* __restrict__ wt2) {
    __shared__ __align__(16) char cNI[TA * SNI_STRIDE];  // 49920 B
    __shared__ __align__(16) char cH[TA * SH_STRIDE];    // 25344 B
    __shared__ float sOut[P_ * TA];
    __shared__ float sSeg[BSEG];

    const int tid  = threadIdx.x;
    const int lane = tid & 63;
    const int w    = tid >> 6;        // wave id: owns cols [w*32, w*32+32)
    const int aB   = blockIdx.x * TA;
    const int rA   = lane & 15;       // A-frag row within 16-tile
    const int q16  = 16 * (lane >> 4);// A-frag k-subgroup byte offset

    if (tid < P_ * TA) sOut[tid] = 0.f;
    if (tid < BSEG)    sSeg[tid] = 0.f;

    // ---- gather node_input = [r[a0]+r[a2], r[a1]] -> LDS bf16 ----
#pragma unroll
    for (int it = 0; it < 6; ++it) {
        int c   = it * NTHREADS + tid;       // 3072 chunks of 8 elems
        int row = c >> 6;
        int k0  = (c & 63) * 8;
        int a   = min(aB + row, A_TOTAL - 1);   // tail rows: dup last angle (discarded)
        int i0 = ang[3 * a], i1 = ang[3 * a + 1], i2 = ang[3 * a + 2];
        float v[8];
        if (k0 < FR_) {
            const float4* p0 = (const float4*)(r + (size_t)i0 * FR_ + k0);
            const float4* p2 = (const float4*)(r + (size_t)i2 * FR_ + k0);
            float4 x0 = p0[0], x1 = p0[1], y0 = p2[0], y1 = p2[1];
            v[0] = x0.x + y0.x; v[1] = x0.y + y0.y; v[2] = x0.z + y0.z; v[3] = x0.w + y0.w;
            v[4] = x1.x + y1.x; v[5] = x1.y + y1.y; v[6] = x1.z + y1.z; v[7] = x1.w + y1.w;
        } else {
            const float4* p1 = (const float4*)(r + (size_t)i1 * FR_ + (k0 - FR_));
            float4 x0 = p1[0], x1 = p1[1];
            v[0] = x0.x; v[1] = x0.y; v[2] = x0.z; v[3] = x0.w;
            v[4] = x1.x; v[5] = x1.y; v[6] = x1.z; v[7] = x1.w;
        }
        uint4 pk;
        pk.x = pk2(v[0], v[1]); pk.y = pk2(v[2], v[3]);
        pk.z = pk2(v[4], v[5]); pk.w = pk2(v[6], v[7]);
        *reinterpret_cast<uint4*>(cNI + row * SNI_STRIDE + k0 * 2) = pk;
    }
    __syncthreads();

    // B-prefetch macro: load chunk c (2 s-steps x 2 ntiles) into buffer buf.
#define LDB(pb, bp0, bp1, c)                                                     \
    {                                                                            \
        pb[0][0] = *(const bf16x8*)((bp0) + (size_t)((c) * 2 + 0) * 8192);       \
        pb[1][0] = *(const bf16x8*)((bp1) + (size_t)((c) * 2 + 0) * 8192);       \
        pb[0][1] = *(const bf16x8*)((bp0) + (size_t)((c) * 2 + 1) * 8192);       \
        pb[1][1] = *(const bf16x8*)((bp1) + (size_t)((c) * 2 + 1) * 8192);       \
    }

    for (int p = 0; p < P_; ++p) {
        // ---------------- layer 1: [48x512] @ [512x256], wave cols w*32.. ----
        const float bias10 = b1[p * H_ + w * 32 + rA];
        const float bias11 = b1[p * H_ + w * 32 + 16 + rA];
        f32x4 acc[3][2];
#pragma unroll
        for (int mt = 0; mt < 3; ++mt) {
            acc[mt][0] = (f32x4){bias10, bias10, bias10, bias10};
            acc[mt][1] = (f32x4){bias11, bias11, bias11, bias11};
        }
        {
            const char* aBase = cNI + rA * SNI_STRIDE + q16;
            const unsigned short* bp0 = wt1 + (size_t)p * 131072 + (size_t)(w * 2 * 64 + lane) * 8;
            const unsigned short* bp1 = bp0 + 512;   // next ntile
            bf16x8 pbA[2][2], pbB[2][2];             // [ntile][js]
            LDB(pbA, bp0, bp1, 0);
#pragma unroll
            for (int c = 0; c < 8; ++c) {            // 8 chunks x 2 s-steps
                if (c & 1) {
                    if (c < 7) LDB(pbA, bp0, bp1, c + 1);
#pragma unroll
                    for (int js = 0; js < 2; ++js) {
                        int s = c * 2 + js;
                        bf16x8 a0 = *(const bf16x8*)(aBase + 64 * s);
                        bf16x8 a1 = *(const bf16x8*)(aBase + 16 * SNI_STRIDE + 64 * s);
                        bf16x8 a2 = *(const bf16x8*)(aBase + 32 * SNI_STRIDE + 64 * s);
                        acc[0][0] = mfma16(a0, pbB[0][js], acc[0][0]);
                        acc[1][0] = mfma16(a1, pbB[0][js], acc[1][0]);
                        acc[2][0] = mfma16(a2, pbB[0][js], acc[2][0]);
                        acc[0][1] = mfma16(a0, pbB[1][js], acc[0][1]);
                        acc[1][1] = mfma16(a1, pbB[1][js], acc[1][1]);
                        acc[2][1] = mfma16(a2, pbB[1][js], acc[2][1]);
                    }
                } else {
                    if (c < 7) LDB(pbB, bp0, bp1, c + 1);
#pragma unroll
                    for (int js = 0; js < 2; ++js) {
                        int s = c * 2 + js;
                        bf16x8 a0 = *(const bf16x8*)(aBase + 64 * s);
                        bf16x8 a1 = *(const bf16x8*)(aBase + 16 * SNI_STRIDE + 64 * s);
                        bf16x8 a2 = *(const bf16x8*)(aBase + 32 * SNI_STRIDE + 64 * s);
                        acc[0][0] = mfma16(a0, pbA[0][js], acc[0][0]);
                        acc[1][0] = mfma16(a1, pbA[0][js], acc[1][0]);
                        acc[2][0] = mfma16(a2, pbA[0][js], acc[2][0]);
                        acc[0][1] = mfma16(a0, pbA[1][js], acc[0][1]);
                        acc[1][1] = mfma16(a1, pbA[1][js], acc[1][1]);
                        acc[2][1] = mfma16(a2, pbA[1][js], acc[2][1]);
                    }
                }
            }
        }
        {   // tanh + packed bf16 -> cH (D layout: row = 4*(l>>4)+i, col = l&15)
#pragma unroll
            for (int nt = 0; nt < 2; ++nt) {
                int col = w * 32 + nt * 16 + rA;
#pragma unroll
                for (int mt = 0; mt < 3; ++mt) {
                    float t0 = fast_tanh(acc[mt][nt][0]);
                    float t1 = fast_tanh(acc[mt][nt][1]);
                    float t2 = fast_tanh(acc[mt][nt][2]);
                    float t3 = fast_tanh(acc[mt][nt][3]);
                    unsigned int u01 = pk2(t0, t1);
                    unsigned int u23 = pk2(t2, t3);
                    char* base = cH + (mt * 16 + (lane >> 4) * 4) * SH_STRIDE + col * 2;
                    *(unsigned short*)(base)                 = (unsigned short)(u01 & 0xffff);
                    *(unsigned short*)(base + SH_STRIDE)     = (unsigned short)(u01 >> 16);
                    *(unsigned short*)(base + 2 * SH_STRIDE) = (unsigned short)(u23 & 0xffff);
                    *(unsigned short*)(base + 3 * SH_STRIDE) = (unsigned short)(u23 >> 16);
                }
            }
        }
        __syncthreads();

        // ---------------- layer 2: [48x256] @ [256x256] ----------------
        const float bias20 = b2[p * H_ + w * 32 + rA];
        const float bias21 = b2[p * H_ + w * 32 + 16 + rA];
        f32x4 acc2[3][2];
#pragma unroll
        for (int mt = 0; mt < 3; ++mt) {
            acc2[mt][0] = (f32x4){bias20, bias20, bias20, bias20};
            acc2[mt][1] = (f32x4){bias21, bias21, bias21, bias21};
        }
        {
            const char* aBase = cH + rA * SH_STRIDE + q16;
            const unsigned short* bp0 = wt2 + (size_t)p * 65536 + (size_t)(w * 2 * 64 + lane) * 8;
            const unsigned short* bp1 = bp0 + 512;
            bf16x8 pbA[2][2], pbB[2][2];
            LDB(pbA, bp0, bp1, 0);
#pragma unroll
            for (int c = 0; c < 4; ++c) {            // 4 chunks x 2 s-steps
                if (c & 1) {
                    if (c < 3) LDB(pbA, bp0, bp1, c + 1);
#pragma unroll
                    for (int js = 0; js < 2; ++js) {
                        int s = c * 2 + js;
                        bf16x8 a0 = *(const bf16x8*)(aBase + 64 * s);
                        bf16x8 a1 = *(const bf16x8*)(aBase + 16 * SH_STRIDE + 64 * s);
                        bf16x8 a2 = *(const bf16x8*)(aBase + 32 * SH_STRIDE + 64 * s);
                        acc2[0][0] = mfma16(a0, pbB[0][js], acc2[0][0]);
                        acc2[1][0] = mfma16(a1, pbB[0][js], acc2[1][0]);
                        acc2[2][0] = mfma16(a2, pbB[0][js], acc2[2][0]);
                        acc2[0][1] = mfma16(a0, pbB[1][js], acc2[0][1]);
                        acc2[1][1] = mfma16(a1, pbB[1][js], acc2[1][1]);
                        acc2[2][1] = mfma16(a2, pbB[1][js], acc2[2][1]);
                    }
                } else {
                    if (c < 3) LDB(pbB, bp0, bp1, c + 1);
#pragma unroll
                    for (int js = 0; js < 2; ++js) {
                        int s = c * 2 + js;
                        bf16x8 a0 = *(const bf16x8*)(aBase + 64 * s);
                        bf16x8 a1 = *(const bf16x8*)(aBase + 16 * SH_STRIDE + 64 * s);
                        bf16x8 a2 = *(const bf16x8*)(aBase + 32 * SH_STRIDE + 64 * s);
                        acc2[0][0] = mfma16(a0, pbA[0][js], acc2[0][0]);
                        acc2[1][0] = mfma16(a1, pbA[0][js], acc2[1][0]);
                        acc2[2][0] = mfma16(a2, pbA[0][js], acc2[2][0]);
                        acc2[0][1] = mfma16(a0, pbA[1][js], acc2[0][1]);
                        acc2[1][1] = mfma16(a1, pbA[1][js], acc2[1][1]);
                        acc2[2][1] = mfma16(a2, pbA[1][js], acc2[2][1]);
                    }
                }
            }
        }

        // ---- layer 3 from registers: out[p][a] = sum_n tanh(acc2)[a][n]*w3[n] ----
        {
            const float* w3p = W3 + p * H_;
            float prt[12];
#pragma unroll
            for (int k = 0; k < 12; ++k) prt[k] = 0.f;
#pragma unroll
            for (int nt = 0; nt < 2; ++nt) {
                float wv = w3p[w * 32 + nt * 16 + rA];
#pragma unroll
                for (int mt = 0; mt < 3; ++mt)
#pragma unroll
                    for (int i = 0; i < 4; ++i)
                        prt[mt * 4 + i] += fast_tanh(acc2[mt][nt][i]) * wv;
            }
#pragma unroll
            for (int st = 1; st < 16; st <<= 1)
#pragma unroll
                for (int k = 0; k < 12; ++k) prt[k] += __shfl_xor(prt[k], st);
            if (rA == 0) {
                int rg = (lane >> 4) * 4;
#pragma unroll
                for (int mt = 0; mt < 3; ++mt)
#pragma unroll
                    for (int i = 0; i < 4; ++i)
                        atomicAdd(&sOut[p * TA + mt * 16 + rg + i], prt[mt * 4 + i]);
            }
        }
        __syncthreads();   // cH reads done (next p overwrites) + sOut[p] visible
    }

    // ---------------- geometry + energy + segment sum ----------------
    if (tid < TA && (aB + tid) < A_TOTAL) {
        int a = aB + tid;
        int i0 = ang[3 * a], i1 = ang[3 * a + 1], i2 = ang[3 * a + 2];
        float ax = xyz[3 * i0], ay = xyz[3 * i0 + 1], az = xyz[3 * i0 + 2];
        float bx = xyz[3 * i1], by = xyz[3 * i1 + 1], bz = xyz[3 * i1 + 2];
        float cx = xyz[3 * i2], cy = xyz[3 * i2 + 1], cz = xyz[3 * i2 + 2];
        float v1x = bx - ax, v1y = by - ay, v1z = bz - az;
        float v2x = cx - bx, v2y = cy - by, v2z = cz - bz;
        float dot = -(v1x * v2x + v1y * v2y + v1z * v2z);
        float n1  = v1x * v1x + v1y * v1y + v1z * v1z;
        float n2  = v2x * v2x + v2y * v2y + v2z * v2z;
        float ct  = dot / sqrtf(n1 * n2);
        float th  = acosf(ct / 1.000001f);

        float o0 = sOut[0 * TA + tid] + b3[0], o1 = sOut[1 * TA + tid] + b3[1];
        float o2 = sOut[2 * TA + tid] + b3[2], o3 = sOut[3 * TA + tid] + b3[3];
        float o4 = sOut[4 * TA + tid] + b3[4], o5 = sOut[5 * TA + tid] + b3[5];
        float t0h = (1.38243827f + o0); t0h *= t0h;       // (sqrt(109.5*pi/180)+o0)^2
        float kh  = (3.16227766f + o1); kh  *= kh;        // (sqrt(10)+o1)^2
        float d   = th - t0h;
        float E   = 0.5f * kh * d * d;
        float t0c = o2 * o2, kc = o3 * o3;
        float dc  = th - t0c;
        E += 0.5f * kc * dc * dc * dc;
        float t0q = o4 * o4, kq = o5 * o5;
        float dq  = th - t0q;
        E += 0.5f * kq * dq * dq * dq * dq;

        int lo = 0, hi = BSEG - 1;                        // last s with prefix[s] <= a
        while (lo < hi) { int mid = (lo + hi + 1) >> 1; if (prefix[mid] <= a) lo = mid; else hi = mid - 1; }
        atomicAdd(&sSeg[lo], E);
    }
    __syncthreads();
    if (tid < BSEG) {
        float v = sSeg[tid];
        if (v != 0.f) atomicAdd(out + tid, v);
    }
}

extern "C" void kernel_launch(void* const* d_in, const int* in_sizes, int n_in,
                              void* d_out, int out_size, void* d_ws, size_t ws_size,
                              hipStream_t stream) {
    const float* r   = (const float*)d_in[0];
    const float* xyz = (const float*)d_in[1];
    const int*   ang = (const int*)d_in[2];
    const int*   na  = (const int*)d_in[3];
    const float* W1  = (const float*)d_in[4];
    const float* b1  = (const float*)d_in[5];
    const float* W2  = (const float*)d_in[6];
    const float* b2  = (const float*)d_in[7];
    const float* W3  = (const float*)d_in[8];
    const float* b3  = (const float*)d_in[9];
    float* out = (float*)d_out;

    char* ws = (char*)d_ws;
    int* prefix          = (int*)ws;                              // 101 ints (512B reserved)
    unsigned short* wt1  = (unsigned short*)(ws + 512);           // 1.5 MB bf16 frag-linear
    unsigned short* wt2  = (unsigned short*)(ws + 512 + 1572864); // 0.75 MB

    prep_kernel<<<576, 256, 0, stream>>>(W1, W2, na, out, prefix, wt1, wt2);
    int nblk = (A_TOTAL + TA - 1) / TA;   // 4167 (last block: 32 live rows)
    angle_main<<<nblk, NTHREADS, 0, stream>>>(r, xyz, ang, b1, b2, W3, b3, out, prefix, wt1, wt2);
}